// Round 1
// baseline (885.299 us; speedup 1.0000x reference)
//
#include <hip/hip_runtime.h>
#include <hip/hip_bf16.h>

// ---------------------------------------------------------------------------
// EncoderGNN: 3-layer GINE encoder, N=50000 nodes, E=800000 edges, H=128.
//   h = type_embed[x_type] + x_feat@featW + featb
//   per layer: m = relu(h[src] + edge_attr@edgeW + edgeb)  (e recomputed!)
//              agg = segment_sum(m, dst)
//              z = (1+eps)*h + agg
//              h = relu( relu(z@W1+b1) @ W2 + b2 )
//   out = h @ Wout + bout
// Strategy: device-built CSR (count/scan/fill), per-dst gather aggregation,
// fused 2-GEMM MLP with 4x4 register blocking (all f32, no atomics on floats).
// ---------------------------------------------------------------------------

#define HDIM 128

__global__ void count_kernel(const int* __restrict__ dstIdx, int* __restrict__ deg, int E) {
    int e = blockIdx.x * blockDim.x + threadIdx.x;
    if (e < E) atomicAdd(&deg[dstIdx[e]], 1);
}

__global__ __launch_bounds__(1024) void scan_kernel(const int* __restrict__ deg,
                                                    int* __restrict__ row_ptr,
                                                    int* __restrict__ fill_ptr, int N) {
    __shared__ int sums[1024];
    const int tid = threadIdx.x;
    const int per = (N + 1023) >> 10;
    const int start = tid * per;
    const int end   = min(start + per, N);
    int s = 0;
    for (int i = start; i < end; ++i) s += deg[i];
    sums[tid] = s;
    __syncthreads();
    // inclusive Hillis-Steele scan over 1024 partials
    for (int off = 1; off < 1024; off <<= 1) {
        int v = (tid >= off) ? sums[tid - off] : 0;
        __syncthreads();
        sums[tid] += v;
        __syncthreads();
    }
    int run = (tid > 0) ? sums[tid - 1] : 0;   // exclusive prefix
    for (int i = start; i < end; ++i) {
        row_ptr[i]  = run;
        fill_ptr[i] = run;
        run += deg[i];
    }
    if (tid == 1023) row_ptr[N] = run;          // == E
}

__global__ void fill_kernel(const int* __restrict__ srcIdx, const int* __restrict__ dstIdx,
                            const float* __restrict__ edge_attr,
                            int* __restrict__ fill_ptr,
                            int* __restrict__ adj_src, float4* __restrict__ adj_ea, int E) {
    int e = blockIdx.x * blockDim.x + threadIdx.x;
    if (e < E) {
        int d = dstIdx[e];
        int pos = atomicAdd(&fill_ptr[d], 1);
        adj_src[pos] = srcIdx[e];
        adj_ea[pos]  = *(const float4*)(edge_attr + (size_t)e * 4);
    }
}

__global__ void embed_kernel(const int* __restrict__ x_type, const float* __restrict__ x_feat,
                             const float* __restrict__ type_embed, const float* __restrict__ featW,
                             const float* __restrict__ featb, float* __restrict__ h, int N) {
    int idx = blockIdx.x * 256 + threadIdx.x;
    int n = idx >> 7, c = idx & 127;
    if (n >= N) return;
    int t = x_type[n];
    float acc = type_embed[(size_t)t * HDIM + c] + featb[c];
#pragma unroll
    for (int k = 0; k < 7; ++k)
        acc = fmaf(x_feat[(size_t)n * 7 + k], featW[(size_t)k * HDIM + c], acc);
    h[(size_t)n * HDIM + c] = acc;
}

// One 128-thread group per destination node; lane = channel.
__global__ __launch_bounds__(256) void agg_kernel(
        const float* __restrict__ h, const int* __restrict__ row_ptr,
        const int* __restrict__ adj_src, const float4* __restrict__ adj_ea,
        const float* __restrict__ edgeW, const float* __restrict__ edgeb,
        const float* __restrict__ eps, int l, float* __restrict__ z, int N) {
    int node = blockIdx.x * 2 + (threadIdx.x >> 7);
    int c = threadIdx.x & 127;
    if (node >= N) return;
    const float w0 = edgeW[c], w1 = edgeW[128 + c], w2 = edgeW[256 + c], w3 = edgeW[384 + c];
    const float eb = edgeb[c];
    const int beg = row_ptr[node], end = row_ptr[node + 1];
    float acc = 0.f;
    for (int i = beg; i < end; ++i) {
        int s = adj_src[i];
        float4 ea = adj_ea[i];
        float e = fmaf(ea.x, w0, fmaf(ea.y, w1, fmaf(ea.z, w2, fmaf(ea.w, w3, eb))));
        float msg = h[(size_t)s * HDIM + c] + e;
        acc += fmaxf(msg, 0.f);
    }
    float ep = 1.0f + eps[l];
    z[(size_t)node * HDIM + c] = fmaf(ep, h[(size_t)node * HDIM + c], acc);
}

__device__ __forceinline__ void fma4(float4& a, const float4 s,
                                     const float4 w0, const float4 w1,
                                     const float4 w2, const float4 w3) {
    a.x = fmaf(s.x, w0.x, a.x); a.y = fmaf(s.x, w0.y, a.y);
    a.z = fmaf(s.x, w0.z, a.z); a.w = fmaf(s.x, w0.w, a.w);
    a.x = fmaf(s.y, w1.x, a.x); a.y = fmaf(s.y, w1.y, a.y);
    a.z = fmaf(s.y, w1.z, a.z); a.w = fmaf(s.y, w1.w, a.w);
    a.x = fmaf(s.z, w2.x, a.x); a.y = fmaf(s.z, w2.y, a.y);
    a.z = fmaf(s.z, w2.z, a.z); a.w = fmaf(s.z, w2.w, a.w);
    a.x = fmaf(s.w, w3.x, a.x); a.y = fmaf(s.w, w3.y, a.y);
    a.z = fmaf(s.w, w3.z, a.z); a.w = fmaf(s.w, w3.w, a.w);
}

__device__ __forceinline__ float4 relu4(float4 v) {
    v.x = fmaxf(v.x, 0.f); v.y = fmaxf(v.y, 0.f);
    v.z = fmaxf(v.z, 0.f); v.w = fmaxf(v.w, 0.f);
    return v;
}

// h_out = relu( relu(z@W1+b1) @ W2 + b2 ), one block = 32 rows, 256 threads,
// each thread computes a 4x4 register tile per phase.
__global__ __launch_bounds__(256) void mlp_kernel(
        const float* __restrict__ z,
        const float* __restrict__ W1, const float* __restrict__ b1,
        const float* __restrict__ W2, const float* __restrict__ b2,
        float* __restrict__ h_out, int N) {
    __shared__ __align__(16) float tile[32][HDIM];
    const int tid = threadIdx.x;
    const int row0 = blockIdx.x * 32;

    // stage z tile (rows beyond N -> zeros)
#pragma unroll
    for (int i = 0; i < 4; ++i) {
        int idx = tid + i * 256;      // float4 slot 0..1023
        int r = idx >> 5, c4 = idx & 31;
        float4 v = make_float4(0.f, 0.f, 0.f, 0.f);
        if (row0 + r < N) v = *(const float4*)(z + (size_t)(row0 + r) * HDIM + c4 * 4);
        *(float4*)(&tile[r][c4 * 4]) = v;
    }
    __syncthreads();

    const int rg = tid >> 5, cg = tid & 31;
    const int r0 = rg * 4, c0 = cg * 4;

    float4 a0, a1, a2, a3;
    // ---- phase 1: t = relu(z @ W1 + b1) ----
    {
        float4 bb = *(const float4*)(b1 + c0);
        a0 = a1 = a2 = a3 = bb;
    }
    for (int k = 0; k < HDIM; k += 4) {
        float4 z0 = *(const float4*)(&tile[r0 + 0][k]);
        float4 z1 = *(const float4*)(&tile[r0 + 1][k]);
        float4 z2 = *(const float4*)(&tile[r0 + 2][k]);
        float4 z3 = *(const float4*)(&tile[r0 + 3][k]);
        float4 w0 = *(const float4*)(W1 + (size_t)(k + 0) * HDIM + c0);
        float4 w1 = *(const float4*)(W1 + (size_t)(k + 1) * HDIM + c0);
        float4 w2 = *(const float4*)(W1 + (size_t)(k + 2) * HDIM + c0);
        float4 w3 = *(const float4*)(W1 + (size_t)(k + 3) * HDIM + c0);
        fma4(a0, z0, w0, w1, w2, w3);
        fma4(a1, z1, w0, w1, w2, w3);
        fma4(a2, z2, w0, w1, w2, w3);
        fma4(a3, z3, w0, w1, w2, w3);
    }
    a0 = relu4(a0); a1 = relu4(a1); a2 = relu4(a2); a3 = relu4(a3);
    __syncthreads();   // everyone done reading z
    *(float4*)(&tile[r0 + 0][c0]) = a0;
    *(float4*)(&tile[r0 + 1][c0]) = a1;
    *(float4*)(&tile[r0 + 2][c0]) = a2;
    *(float4*)(&tile[r0 + 3][c0]) = a3;
    __syncthreads();

    // ---- phase 2: h = relu(t @ W2 + b2) ----
    {
        float4 bb = *(const float4*)(b2 + c0);
        a0 = a1 = a2 = a3 = bb;
    }
    for (int k = 0; k < HDIM; k += 4) {
        float4 z0 = *(const float4*)(&tile[r0 + 0][k]);
        float4 z1 = *(const float4*)(&tile[r0 + 1][k]);
        float4 z2 = *(const float4*)(&tile[r0 + 2][k]);
        float4 z3 = *(const float4*)(&tile[r0 + 3][k]);
        float4 w0 = *(const float4*)(W2 + (size_t)(k + 0) * HDIM + c0);
        float4 w1 = *(const float4*)(W2 + (size_t)(k + 1) * HDIM + c0);
        float4 w2 = *(const float4*)(W2 + (size_t)(k + 2) * HDIM + c0);
        float4 w3 = *(const float4*)(W2 + (size_t)(k + 3) * HDIM + c0);
        fma4(a0, z0, w0, w1, w2, w3);
        fma4(a1, z1, w0, w1, w2, w3);
        fma4(a2, z2, w0, w1, w2, w3);
        fma4(a3, z3, w0, w1, w2, w3);
    }
    a0 = relu4(a0); a1 = relu4(a1); a2 = relu4(a2); a3 = relu4(a3);
#pragma unroll
    for (int r = 0; r < 4; ++r) {
        if (row0 + r0 + r < N) {
            float4 v = (r == 0) ? a0 : (r == 1) ? a1 : (r == 2) ? a2 : a3;
            *(float4*)(h_out + (size_t)(row0 + r0 + r) * HDIM + c0) = v;
        }
    }
}

__global__ void out_kernel(const float* __restrict__ h, const float* __restrict__ Wout,
                           const float* __restrict__ bout, float* __restrict__ out, int N) {
    int idx = blockIdx.x * 256 + threadIdx.x;
    int n = idx >> 4, pe = idx & 15;
    if (n >= N) return;
    float acc = bout[pe];
#pragma unroll 8
    for (int k = 0; k < HDIM; ++k)
        acc = fmaf(h[(size_t)n * HDIM + k], Wout[k * 16 + pe], acc);
    out[(size_t)n * 16 + pe] = acc;
}

extern "C" void kernel_launch(void* const* d_in, const int* in_sizes, int n_in,
                              void* d_out, int out_size, void* d_ws, size_t ws_size,
                              hipStream_t stream) {
    const int*   x_type     = (const int*)  d_in[0];
    const float* x_feat     = (const float*)d_in[1];
    const int*   edge_index = (const int*)  d_in[2];
    const float* edge_attr  = (const float*)d_in[3];
    const float* type_embed = (const float*)d_in[4];
    const float* featW      = (const float*)d_in[5];
    const float* featb      = (const float*)d_in[6];
    const float* edgeW      = (const float*)d_in[7];
    const float* edgeb      = (const float*)d_in[8];
    const float* W1         = (const float*)d_in[9];
    const float* b1         = (const float*)d_in[10];
    const float* W2         = (const float*)d_in[11];
    const float* b2         = (const float*)d_in[12];
    const float* eps        = (const float*)d_in[13];
    const float* Wout       = (const float*)d_in[14];
    const float* bout       = (const float*)d_in[15];

    const int N = in_sizes[0];
    const int E = in_sizes[2] / 2;
    const int L = in_sizes[13];

    const int* srcIdx = edge_index;
    const int* dstIdx = edge_index + E;

    // workspace carve-up (256B aligned)
    auto align256 = [](size_t x) { return (x + 255) & ~(size_t)255; };
    char* p = (char*)d_ws;
    float* h_buf    = (float*)p;               p += align256((size_t)N * HDIM * 4);
    float* z_buf    = (float*)p;               p += align256((size_t)N * HDIM * 4);
    int*   deg      = (int*)p;                 p += align256((size_t)N * 4);
    int*   row_ptr  = (int*)p;                 p += align256((size_t)(N + 1) * 4);
    int*   fill_ptr = (int*)p;                 p += align256((size_t)N * 4);
    int*   adj_src  = (int*)p;                 p += align256((size_t)E * 4);
    float4* adj_ea  = (float4*)p;              p += align256((size_t)E * 16);
    (void)ws_size;

    // ---- CSR build ----
    hipMemsetAsync(deg, 0, (size_t)N * 4, stream);
    count_kernel<<<(E + 255) / 256, 256, 0, stream>>>(dstIdx, deg, E);
    scan_kernel<<<1, 1024, 0, stream>>>(deg, row_ptr, fill_ptr, N);
    fill_kernel<<<(E + 255) / 256, 256, 0, stream>>>(srcIdx, dstIdx, edge_attr,
                                                     fill_ptr, adj_src, adj_ea, E);

    // ---- node embedding ----
    embed_kernel<<<((size_t)N * HDIM + 255) / 256, 256, 0, stream>>>(
        x_type, x_feat, type_embed, featW, featb, h_buf, N);

    // ---- GIN layers ----
    for (int l = 0; l < L; ++l) {
        agg_kernel<<<(N + 1) / 2, 256, 0, stream>>>(
            h_buf, row_ptr, adj_src, adj_ea, edgeW, edgeb, eps, l, z_buf, N);
        mlp_kernel<<<(N + 31) / 32, 256, 0, stream>>>(
            z_buf, W1 + (size_t)l * HDIM * HDIM, b1 + (size_t)l * HDIM,
            W2 + (size_t)l * HDIM * HDIM, b2 + (size_t)l * HDIM, h_buf, N);
    }

    // ---- output projection ----
    out_kernel<<<((size_t)N * 16 + 255) / 256, 256, 0, stream>>>(
        h_buf, Wout, bout, (float*)d_out, N);
}

// Round 2
// 571.434 us; speedup vs baseline: 1.5493x; 1.5493x over previous
//
#include <hip/hip_runtime.h>
#include <hip/hip_bf16.h>

// ---------------------------------------------------------------------------
// EncoderGNN: 3-layer GINE encoder, N=50000, E=800000, H=128.
// Round 2: h stored in bf16 (halves gather traffic, better L2 fit);
// agg_kernel = 1 wave/node, lane owns 2 channels (packed bf16x2 loads),
// edge loop unrolled x4 for 4 gathers in flight (latency-bound fix).
// MLP stays f32 vector-FMA, writes bf16 h. All scatter-free via device CSR.
// ---------------------------------------------------------------------------

#define HDIM 128

typedef unsigned int uint32;
typedef unsigned short ushort16;

__device__ __forceinline__ ushort16 f2bf(float f) {
    uint32 u = __float_as_uint(f);
    u += 0x7fff + ((u >> 16) & 1);      // round-to-nearest-even
    return (ushort16)(u >> 16);
}
__device__ __forceinline__ float bflo(uint32 g) { return __uint_as_float(g << 16); }
__device__ __forceinline__ float bfhi(uint32 g) { return __uint_as_float(g & 0xffff0000u); }

// ---------------- CSR build ----------------
__global__ void count_kernel(const int* __restrict__ dstIdx, int* __restrict__ deg, int E) {
    int e = blockIdx.x * blockDim.x + threadIdx.x;
    if (e < E) atomicAdd(&deg[dstIdx[e]], 1);
}

__global__ __launch_bounds__(1024) void scan_kernel(const int* __restrict__ deg,
                                                    int* __restrict__ row_ptr,
                                                    int* __restrict__ fill_ptr, int N) {
    __shared__ int sums[1024];
    const int tid = threadIdx.x;
    const int per = (N + 1023) >> 10;
    const int start = tid * per;
    const int end   = min(start + per, N);
    int s = 0;
    for (int i = start; i < end; ++i) s += deg[i];
    sums[tid] = s;
    __syncthreads();
    for (int off = 1; off < 1024; off <<= 1) {
        int v = (tid >= off) ? sums[tid - off] : 0;
        __syncthreads();
        sums[tid] += v;
        __syncthreads();
    }
    int run = (tid > 0) ? sums[tid - 1] : 0;
    for (int i = start; i < end; ++i) {
        row_ptr[i]  = run;
        fill_ptr[i] = run;
        run += deg[i];
    }
    if (tid == 1023) row_ptr[N] = run;
}

__global__ void fill_kernel(const int* __restrict__ srcIdx, const int* __restrict__ dstIdx,
                            const float* __restrict__ edge_attr,
                            int* __restrict__ fill_ptr,
                            int* __restrict__ adj_src, float4* __restrict__ adj_ea, int E) {
    int e = blockIdx.x * blockDim.x + threadIdx.x;
    if (e < E) {
        int d = dstIdx[e];
        int pos = atomicAdd(&fill_ptr[d], 1);
        adj_src[pos] = srcIdx[e];
        adj_ea[pos]  = *(const float4*)(edge_attr + (size_t)e * 4);
    }
}

// ---------------- node embedding (writes bf16 h) ----------------
__global__ void embed_kernel(const int* __restrict__ x_type, const float* __restrict__ x_feat,
                             const float* __restrict__ type_embed, const float* __restrict__ featW,
                             const float* __restrict__ featb, ushort16* __restrict__ h, int N) {
    int idx = blockIdx.x * 256 + threadIdx.x;
    int n = idx >> 7, c = idx & 127;
    if (n >= N) return;
    int t = x_type[n];
    float acc = type_embed[(size_t)t * HDIM + c] + featb[c];
#pragma unroll
    for (int k = 0; k < 7; ++k)
        acc = fmaf(x_feat[(size_t)n * 7 + k], featW[(size_t)k * HDIM + c], acc);
    h[(size_t)n * HDIM + c] = f2bf(acc);
}

// ---------------- aggregation: 1 wave per node, lane = 2 channels ----------------
__global__ __launch_bounds__(256) void agg_kernel(
        const uint32* __restrict__ hq,       // [N][64] packed bf16x2
        const int* __restrict__ row_ptr,
        const int* __restrict__ adj_src, const float4* __restrict__ adj_ea,
        const float* __restrict__ edgeW, const float* __restrict__ edgeb,
        const float* __restrict__ eps, int l, float* __restrict__ z, int N) {
    const int node = blockIdx.x * 4 + (threadIdx.x >> 6);
    const int lane = threadIdx.x & 63;
    if (node >= N) return;
    const int c0 = 2 * lane;
    const float w0l = edgeW[c0],       w0h = edgeW[c0 + 1];
    const float w1l = edgeW[128 + c0], w1h = edgeW[128 + c0 + 1];
    const float w2l = edgeW[256 + c0], w2h = edgeW[256 + c0 + 1];
    const float w3l = edgeW[384 + c0], w3h = edgeW[384 + c0 + 1];
    const float ebl = edgeb[c0],       ebh = edgeb[c0 + 1];

    const int beg = row_ptr[node], end = row_ptr[node + 1];
    float acc0 = 0.f, acc1 = 0.f;

    int i = beg;
    for (; i + 4 <= end; i += 4) {
        int s0 = adj_src[i], s1 = adj_src[i + 1], s2 = adj_src[i + 2], s3 = adj_src[i + 3];
        float4 ea0 = adj_ea[i], ea1 = adj_ea[i + 1], ea2 = adj_ea[i + 2], ea3 = adj_ea[i + 3];
        uint32 g0 = hq[(size_t)s0 * 64 + lane];
        uint32 g1 = hq[(size_t)s1 * 64 + lane];
        uint32 g2 = hq[(size_t)s2 * 64 + lane];
        uint32 g3 = hq[(size_t)s3 * 64 + lane];
        float e0l = fmaf(ea0.x, w0l, fmaf(ea0.y, w1l, fmaf(ea0.z, w2l, fmaf(ea0.w, w3l, ebl))));
        float e0h = fmaf(ea0.x, w0h, fmaf(ea0.y, w1h, fmaf(ea0.z, w2h, fmaf(ea0.w, w3h, ebh))));
        float e1l = fmaf(ea1.x, w0l, fmaf(ea1.y, w1l, fmaf(ea1.z, w2l, fmaf(ea1.w, w3l, ebl))));
        float e1h = fmaf(ea1.x, w0h, fmaf(ea1.y, w1h, fmaf(ea1.z, w2h, fmaf(ea1.w, w3h, ebh))));
        float e2l = fmaf(ea2.x, w0l, fmaf(ea2.y, w1l, fmaf(ea2.z, w2l, fmaf(ea2.w, w3l, ebl))));
        float e2h = fmaf(ea2.x, w0h, fmaf(ea2.y, w1h, fmaf(ea2.z, w2h, fmaf(ea2.w, w3h, ebh))));
        float e3l = fmaf(ea3.x, w0l, fmaf(ea3.y, w1l, fmaf(ea3.z, w2l, fmaf(ea3.w, w3l, ebl))));
        float e3h = fmaf(ea3.x, w0h, fmaf(ea3.y, w1h, fmaf(ea3.z, w2h, fmaf(ea3.w, w3h, ebh))));
        acc0 += fmaxf(bflo(g0) + e0l, 0.f);  acc1 += fmaxf(bfhi(g0) + e0h, 0.f);
        acc0 += fmaxf(bflo(g1) + e1l, 0.f);  acc1 += fmaxf(bfhi(g1) + e1h, 0.f);
        acc0 += fmaxf(bflo(g2) + e2l, 0.f);  acc1 += fmaxf(bfhi(g2) + e2h, 0.f);
        acc0 += fmaxf(bflo(g3) + e3l, 0.f);  acc1 += fmaxf(bfhi(g3) + e3h, 0.f);
    }
    for (; i < end; ++i) {
        int s = adj_src[i];
        float4 ea = adj_ea[i];
        uint32 g = hq[(size_t)s * 64 + lane];
        float el = fmaf(ea.x, w0l, fmaf(ea.y, w1l, fmaf(ea.z, w2l, fmaf(ea.w, w3l, ebl))));
        float eh = fmaf(ea.x, w0h, fmaf(ea.y, w1h, fmaf(ea.z, w2h, fmaf(ea.w, w3h, ebh))));
        acc0 += fmaxf(bflo(g) + el, 0.f);
        acc1 += fmaxf(bfhi(g) + eh, 0.f);
    }

    const float ep = 1.0f + eps[l];
    uint32 gs = hq[(size_t)node * 64 + lane];
    float2 zv;
    zv.x = fmaf(ep, bflo(gs), acc0);
    zv.y = fmaf(ep, bfhi(gs), acc1);
    *(float2*)(z + (size_t)node * HDIM + c0) = zv;
}

// ---------------- fused 2-GEMM MLP (f32), writes bf16 h ----------------
__device__ __forceinline__ void fma4(float4& a, const float4 s,
                                     const float4 w0, const float4 w1,
                                     const float4 w2, const float4 w3) {
    a.x = fmaf(s.x, w0.x, a.x); a.y = fmaf(s.x, w0.y, a.y);
    a.z = fmaf(s.x, w0.z, a.z); a.w = fmaf(s.x, w0.w, a.w);
    a.x = fmaf(s.y, w1.x, a.x); a.y = fmaf(s.y, w1.y, a.y);
    a.z = fmaf(s.y, w1.z, a.z); a.w = fmaf(s.y, w1.w, a.w);
    a.x = fmaf(s.z, w2.x, a.x); a.y = fmaf(s.z, w2.y, a.y);
    a.z = fmaf(s.z, w2.z, a.z); a.w = fmaf(s.z, w2.w, a.w);
    a.x = fmaf(s.w, w3.x, a.x); a.y = fmaf(s.w, w3.y, a.y);
    a.z = fmaf(s.w, w3.z, a.z); a.w = fmaf(s.w, w3.w, a.w);
}

__device__ __forceinline__ float4 relu4(float4 v) {
    v.x = fmaxf(v.x, 0.f); v.y = fmaxf(v.y, 0.f);
    v.z = fmaxf(v.z, 0.f); v.w = fmaxf(v.w, 0.f);
    return v;
}

__global__ __launch_bounds__(256) void mlp_kernel(
        const float* __restrict__ z,
        const float* __restrict__ W1, const float* __restrict__ b1,
        const float* __restrict__ W2, const float* __restrict__ b2,
        ushort16* __restrict__ h_out, int N) {
    __shared__ __align__(16) float tile[32][HDIM];
    const int tid = threadIdx.x;
    const int row0 = blockIdx.x * 32;

#pragma unroll
    for (int i = 0; i < 4; ++i) {
        int idx = tid + i * 256;
        int r = idx >> 5, c4 = idx & 31;
        float4 v = make_float4(0.f, 0.f, 0.f, 0.f);
        if (row0 + r < N) v = *(const float4*)(z + (size_t)(row0 + r) * HDIM + c4 * 4);
        *(float4*)(&tile[r][c4 * 4]) = v;
    }
    __syncthreads();

    const int rg = tid >> 5, cg = tid & 31;
    const int r0 = rg * 4, c0 = cg * 4;

    float4 a0, a1, a2, a3;
    {
        float4 bb = *(const float4*)(b1 + c0);
        a0 = a1 = a2 = a3 = bb;
    }
    for (int k = 0; k < HDIM; k += 4) {
        float4 z0 = *(const float4*)(&tile[r0 + 0][k]);
        float4 z1 = *(const float4*)(&tile[r0 + 1][k]);
        float4 z2 = *(const float4*)(&tile[r0 + 2][k]);
        float4 z3 = *(const float4*)(&tile[r0 + 3][k]);
        float4 w0 = *(const float4*)(W1 + (size_t)(k + 0) * HDIM + c0);
        float4 w1 = *(const float4*)(W1 + (size_t)(k + 1) * HDIM + c0);
        float4 w2 = *(const float4*)(W1 + (size_t)(k + 2) * HDIM + c0);
        float4 w3 = *(const float4*)(W1 + (size_t)(k + 3) * HDIM + c0);
        fma4(a0, z0, w0, w1, w2, w3);
        fma4(a1, z1, w0, w1, w2, w3);
        fma4(a2, z2, w0, w1, w2, w3);
        fma4(a3, z3, w0, w1, w2, w3);
    }
    a0 = relu4(a0); a1 = relu4(a1); a2 = relu4(a2); a3 = relu4(a3);
    __syncthreads();
    *(float4*)(&tile[r0 + 0][c0]) = a0;
    *(float4*)(&tile[r0 + 1][c0]) = a1;
    *(float4*)(&tile[r0 + 2][c0]) = a2;
    *(float4*)(&tile[r0 + 3][c0]) = a3;
    __syncthreads();

    {
        float4 bb = *(const float4*)(b2 + c0);
        a0 = a1 = a2 = a3 = bb;
    }
    for (int k = 0; k < HDIM; k += 4) {
        float4 z0 = *(const float4*)(&tile[r0 + 0][k]);
        float4 z1 = *(const float4*)(&tile[r0 + 1][k]);
        float4 z2 = *(const float4*)(&tile[r0 + 2][k]);
        float4 z3 = *(const float4*)(&tile[r0 + 3][k]);
        float4 w0 = *(const float4*)(W2 + (size_t)(k + 0) * HDIM + c0);
        float4 w1 = *(const float4*)(W2 + (size_t)(k + 1) * HDIM + c0);
        float4 w2 = *(const float4*)(W2 + (size_t)(k + 2) * HDIM + c0);
        float4 w3 = *(const float4*)(W2 + (size_t)(k + 3) * HDIM + c0);
        fma4(a0, z0, w0, w1, w2, w3);
        fma4(a1, z1, w0, w1, w2, w3);
        fma4(a2, z2, w0, w1, w2, w3);
        fma4(a3, z3, w0, w1, w2, w3);
    }
    a0 = relu4(a0); a1 = relu4(a1); a2 = relu4(a2); a3 = relu4(a3);
#pragma unroll
    for (int r = 0; r < 4; ++r) {
        if (row0 + r0 + r < N) {
            float4 v = (r == 0) ? a0 : (r == 1) ? a1 : (r == 2) ? a2 : a3;
            ushort4 u;
            u.x = f2bf(v.x); u.y = f2bf(v.y); u.z = f2bf(v.z); u.w = f2bf(v.w);
            *(ushort4*)(h_out + (size_t)(row0 + r0 + r) * HDIM + c0) = u;
        }
    }
}

// ---------------- output projection (reads bf16 h) ----------------
__global__ void out_kernel(const uint32* __restrict__ hq, const float* __restrict__ Wout,
                           const float* __restrict__ bout, float* __restrict__ out, int N) {
    int idx = blockIdx.x * 256 + threadIdx.x;
    int n = idx >> 4, pe = idx & 15;
    if (n >= N) return;
    float acc = bout[pe];
#pragma unroll 8
    for (int k2 = 0; k2 < 64; ++k2) {
        uint32 g = hq[(size_t)n * 64 + k2];
        acc = fmaf(bflo(g), Wout[(2 * k2) * 16 + pe], acc);
        acc = fmaf(bfhi(g), Wout[(2 * k2 + 1) * 16 + pe], acc);
    }
    out[(size_t)n * 16 + pe] = acc;
}

extern "C" void kernel_launch(void* const* d_in, const int* in_sizes, int n_in,
                              void* d_out, int out_size, void* d_ws, size_t ws_size,
                              hipStream_t stream) {
    const int*   x_type     = (const int*)  d_in[0];
    const float* x_feat     = (const float*)d_in[1];
    const int*   edge_index = (const int*)  d_in[2];
    const float* edge_attr  = (const float*)d_in[3];
    const float* type_embed = (const float*)d_in[4];
    const float* featW      = (const float*)d_in[5];
    const float* featb      = (const float*)d_in[6];
    const float* edgeW      = (const float*)d_in[7];
    const float* edgeb      = (const float*)d_in[8];
    const float* W1         = (const float*)d_in[9];
    const float* b1         = (const float*)d_in[10];
    const float* W2         = (const float*)d_in[11];
    const float* b2         = (const float*)d_in[12];
    const float* eps        = (const float*)d_in[13];
    const float* Wout       = (const float*)d_in[14];
    const float* bout       = (const float*)d_in[15];

    const int N = in_sizes[0];
    const int E = in_sizes[2] / 2;
    const int L = in_sizes[13];

    const int* srcIdx = edge_index;
    const int* dstIdx = edge_index + E;

    auto align256 = [](size_t x) { return (x + 255) & ~(size_t)255; };
    char* p = (char*)d_ws;
    ushort16* h_buf  = (ushort16*)p;           p += align256((size_t)N * HDIM * 2);
    float* z_buf     = (float*)p;              p += align256((size_t)N * HDIM * 4);
    int*   deg       = (int*)p;                p += align256((size_t)N * 4);
    int*   row_ptr   = (int*)p;                p += align256((size_t)(N + 1) * 4);
    int*   fill_ptr  = (int*)p;                p += align256((size_t)N * 4);
    int*   adj_src   = (int*)p;                p += align256((size_t)E * 4);
    float4* adj_ea   = (float4*)p;             p += align256((size_t)E * 16);
    (void)ws_size;

    hipMemsetAsync(deg, 0, (size_t)N * 4, stream);
    count_kernel<<<(E + 255) / 256, 256, 0, stream>>>(dstIdx, deg, E);
    scan_kernel<<<1, 1024, 0, stream>>>(deg, row_ptr, fill_ptr, N);
    fill_kernel<<<(E + 255) / 256, 256, 0, stream>>>(srcIdx, dstIdx, edge_attr,
                                                     fill_ptr, adj_src, adj_ea, E);

    embed_kernel<<<((size_t)N * HDIM + 255) / 256, 256, 0, stream>>>(
        x_type, x_feat, type_embed, featW, featb, h_buf, N);

    for (int l = 0; l < L; ++l) {
        agg_kernel<<<(N + 3) / 4, 256, 0, stream>>>(
            (const uint32*)h_buf, row_ptr, adj_src, adj_ea, edgeW, edgeb, eps, l, z_buf, N);
        mlp_kernel<<<(N + 31) / 32, 256, 0, stream>>>(
            z_buf, W1 + (size_t)l * HDIM * HDIM, b1 + (size_t)l * HDIM,
            W2 + (size_t)l * HDIM * HDIM, b2 + (size_t)l * HDIM, h_buf, N);
    }

    out_kernel<<<((size_t)N * 16 + 255) / 256, 256, 0, stream>>>(
        (const uint32*)h_buf, Wout, bout, (float*)d_out, N);
}

// Round 3
// 471.394 us; speedup vs baseline: 1.8780x; 1.2122x over previous
//
#include <hip/hip_runtime.h>
#include <hip/hip_bf16.h>

// ---------------------------------------------------------------------------
// EncoderGNN: 3-layer GINE encoder, N=50000, E=800000, H=128.
// Round 3: replace 1-block strided scan (109us!) with 3-phase coalesced
// multi-block scan (~<10us). agg = 1 wave/node bf16x2 gathers, unroll x4.
// MLP = fused 2-GEMM f32 vector-FMA, 4x4 register tiles. Device CSR, no
// float atomics anywhere.
// ---------------------------------------------------------------------------

#define HDIM 128

typedef unsigned int uint32;
typedef unsigned short ushort16;

__device__ __forceinline__ ushort16 f2bf(float f) {
    uint32 u = __float_as_uint(f);
    u += 0x7fff + ((u >> 16) & 1);      // round-to-nearest-even
    return (ushort16)(u >> 16);
}
__device__ __forceinline__ float bflo(uint32 g) { return __uint_as_float(g << 16); }
__device__ __forceinline__ float bfhi(uint32 g) { return __uint_as_float(g & 0xffff0000u); }

// ---------------- CSR build ----------------
__global__ void count_kernel(const int* __restrict__ dstIdx, int* __restrict__ deg, int E) {
    int e = blockIdx.x * blockDim.x + threadIdx.x;
    if (e < E) atomicAdd(&deg[dstIdx[e]], 1);
}

// phase 1: per-block (256-wide) sums of deg, coalesced
__global__ __launch_bounds__(256) void partial_kernel(const int* __restrict__ deg,
                                                      int* __restrict__ partials, int N) {
    __shared__ int red[256];
    int i = blockIdx.x * 256 + threadIdx.x;
    red[threadIdx.x] = (i < N) ? deg[i] : 0;
    __syncthreads();
#pragma unroll
    for (int off = 128; off > 0; off >>= 1) {
        if (threadIdx.x < off) red[threadIdx.x] += red[threadIdx.x + off];
        __syncthreads();
    }
    if (threadIdx.x == 0) partials[blockIdx.x] = red[0];
}

// phase 2: single-block scan over <=256 partials -> exclusive block offsets
__global__ __launch_bounds__(256) void scan_partials_kernel(const int* __restrict__ partials,
                                                            int* __restrict__ offsets,
                                                            int nb, int* __restrict__ row_ptr,
                                                            int N, int E) {
    __shared__ int buf[256];
    int tid = threadIdx.x;
    buf[tid] = (tid < nb) ? partials[tid] : 0;
    __syncthreads();
#pragma unroll
    for (int off = 1; off < 256; off <<= 1) {
        int v = (tid >= off) ? buf[tid - off] : 0;
        __syncthreads();
        buf[tid] += v;
        __syncthreads();
    }
    if (tid < nb) offsets[tid] = buf[tid] - partials[tid];   // exclusive
    if (tid == 0) row_ptr[N] = E;
}

// phase 3: per-block inclusive scan + block offset -> row_ptr / fill_ptr
__global__ __launch_bounds__(256) void scatter_scan_kernel(const int* __restrict__ deg,
                                                           const int* __restrict__ offsets,
                                                           int* __restrict__ row_ptr,
                                                           int* __restrict__ fill_ptr, int N) {
    __shared__ int buf[256];
    int tid = threadIdx.x;
    int i = blockIdx.x * 256 + tid;
    int v = (i < N) ? deg[i] : 0;
    buf[tid] = v;
    __syncthreads();
#pragma unroll
    for (int off = 1; off < 256; off <<= 1) {
        int t = (tid >= off) ? buf[tid - off] : 0;
        __syncthreads();
        buf[tid] += t;
        __syncthreads();
    }
    if (i < N) {
        int excl = buf[tid] - v + offsets[blockIdx.x];
        row_ptr[i]  = excl;
        fill_ptr[i] = excl;
    }
}

__global__ void fill_kernel(const int* __restrict__ srcIdx, const int* __restrict__ dstIdx,
                            const float* __restrict__ edge_attr,
                            int* __restrict__ fill_ptr,
                            int* __restrict__ adj_src, float4* __restrict__ adj_ea, int E) {
    int e = blockIdx.x * blockDim.x + threadIdx.x;
    if (e < E) {
        int d = dstIdx[e];
        int pos = atomicAdd(&fill_ptr[d], 1);
        adj_src[pos] = srcIdx[e];
        adj_ea[pos]  = *(const float4*)(edge_attr + (size_t)e * 4);
    }
}

// ---------------- node embedding (writes bf16 h) ----------------
__global__ void embed_kernel(const int* __restrict__ x_type, const float* __restrict__ x_feat,
                             const float* __restrict__ type_embed, const float* __restrict__ featW,
                             const float* __restrict__ featb, ushort16* __restrict__ h, int N) {
    int idx = blockIdx.x * 256 + threadIdx.x;
    int n = idx >> 7, c = idx & 127;
    if (n >= N) return;
    int t = x_type[n];
    float acc = type_embed[(size_t)t * HDIM + c] + featb[c];
#pragma unroll
    for (int k = 0; k < 7; ++k)
        acc = fmaf(x_feat[(size_t)n * 7 + k], featW[(size_t)k * HDIM + c], acc);
    h[(size_t)n * HDIM + c] = f2bf(acc);
}

// ---------------- aggregation: 1 wave per node, lane = 2 channels ----------------
__global__ __launch_bounds__(256) void agg_kernel(
        const uint32* __restrict__ hq,       // [N][64] packed bf16x2
        const int* __restrict__ row_ptr,
        const int* __restrict__ adj_src, const float4* __restrict__ adj_ea,
        const float* __restrict__ edgeW, const float* __restrict__ edgeb,
        const float* __restrict__ eps, int l, float* __restrict__ z, int N) {
    const int node = blockIdx.x * 4 + (threadIdx.x >> 6);
    const int lane = threadIdx.x & 63;
    if (node >= N) return;
    const int c0 = 2 * lane;
    const float w0l = edgeW[c0],       w0h = edgeW[c0 + 1];
    const float w1l = edgeW[128 + c0], w1h = edgeW[128 + c0 + 1];
    const float w2l = edgeW[256 + c0], w2h = edgeW[256 + c0 + 1];
    const float w3l = edgeW[384 + c0], w3h = edgeW[384 + c0 + 1];
    const float ebl = edgeb[c0],       ebh = edgeb[c0 + 1];

    const int beg = row_ptr[node], end = row_ptr[node + 1];
    float acc0 = 0.f, acc1 = 0.f;

    int i = beg;
    for (; i + 4 <= end; i += 4) {
        int s0 = adj_src[i], s1 = adj_src[i + 1], s2 = adj_src[i + 2], s3 = adj_src[i + 3];
        float4 ea0 = adj_ea[i], ea1 = adj_ea[i + 1], ea2 = adj_ea[i + 2], ea3 = adj_ea[i + 3];
        uint32 g0 = hq[(size_t)s0 * 64 + lane];
        uint32 g1 = hq[(size_t)s1 * 64 + lane];
        uint32 g2 = hq[(size_t)s2 * 64 + lane];
        uint32 g3 = hq[(size_t)s3 * 64 + lane];
        float e0l = fmaf(ea0.x, w0l, fmaf(ea0.y, w1l, fmaf(ea0.z, w2l, fmaf(ea0.w, w3l, ebl))));
        float e0h = fmaf(ea0.x, w0h, fmaf(ea0.y, w1h, fmaf(ea0.z, w2h, fmaf(ea0.w, w3h, ebh))));
        float e1l = fmaf(ea1.x, w0l, fmaf(ea1.y, w1l, fmaf(ea1.z, w2l, fmaf(ea1.w, w3l, ebl))));
        float e1h = fmaf(ea1.x, w0h, fmaf(ea1.y, w1h, fmaf(ea1.z, w2h, fmaf(ea1.w, w3h, ebh))));
        float e2l = fmaf(ea2.x, w0l, fmaf(ea2.y, w1l, fmaf(ea2.z, w2l, fmaf(ea2.w, w3l, ebl))));
        float e2h = fmaf(ea2.x, w0h, fmaf(ea2.y, w1h, fmaf(ea2.z, w2h, fmaf(ea2.w, w3h, ebh))));
        float e3l = fmaf(ea3.x, w0l, fmaf(ea3.y, w1l, fmaf(ea3.z, w2l, fmaf(ea3.w, w3l, ebl))));
        float e3h = fmaf(ea3.x, w0h, fmaf(ea3.y, w1h, fmaf(ea3.z, w2h, fmaf(ea3.w, w3h, ebh))));
        acc0 += fmaxf(bflo(g0) + e0l, 0.f);  acc1 += fmaxf(bfhi(g0) + e0h, 0.f);
        acc0 += fmaxf(bflo(g1) + e1l, 0.f);  acc1 += fmaxf(bfhi(g1) + e1h, 0.f);
        acc0 += fmaxf(bflo(g2) + e2l, 0.f);  acc1 += fmaxf(bfhi(g2) + e2h, 0.f);
        acc0 += fmaxf(bflo(g3) + e3l, 0.f);  acc1 += fmaxf(bfhi(g3) + e3h, 0.f);
    }
    for (; i < end; ++i) {
        int s = adj_src[i];
        float4 ea = adj_ea[i];
        uint32 g = hq[(size_t)s * 64 + lane];
        float el = fmaf(ea.x, w0l, fmaf(ea.y, w1l, fmaf(ea.z, w2l, fmaf(ea.w, w3l, ebl))));
        float eh = fmaf(ea.x, w0h, fmaf(ea.y, w1h, fmaf(ea.z, w2h, fmaf(ea.w, w3h, ebh))));
        acc0 += fmaxf(bflo(g) + el, 0.f);
        acc1 += fmaxf(bfhi(g) + eh, 0.f);
    }

    const float ep = 1.0f + eps[l];
    uint32 gs = hq[(size_t)node * 64 + lane];
    float2 zv;
    zv.x = fmaf(ep, bflo(gs), acc0);
    zv.y = fmaf(ep, bfhi(gs), acc1);
    *(float2*)(z + (size_t)node * HDIM + c0) = zv;
}

// ---------------- fused 2-GEMM MLP (f32), writes bf16 h ----------------
__device__ __forceinline__ void fma4(float4& a, const float4 s,
                                     const float4 w0, const float4 w1,
                                     const float4 w2, const float4 w3) {
    a.x = fmaf(s.x, w0.x, a.x); a.y = fmaf(s.x, w0.y, a.y);
    a.z = fmaf(s.x, w0.z, a.z); a.w = fmaf(s.x, w0.w, a.w);
    a.x = fmaf(s.y, w1.x, a.x); a.y = fmaf(s.y, w1.y, a.y);
    a.z = fmaf(s.y, w1.z, a.z); a.w = fmaf(s.y, w1.w, a.w);
    a.x = fmaf(s.z, w2.x, a.x); a.y = fmaf(s.z, w2.y, a.y);
    a.z = fmaf(s.z, w2.z, a.z); a.w = fmaf(s.z, w2.w, a.w);
    a.x = fmaf(s.w, w3.x, a.x); a.y = fmaf(s.w, w3.y, a.y);
    a.z = fmaf(s.w, w3.z, a.z); a.w = fmaf(s.w, w3.w, a.w);
}

__device__ __forceinline__ float4 relu4(float4 v) {
    v.x = fmaxf(v.x, 0.f); v.y = fmaxf(v.y, 0.f);
    v.z = fmaxf(v.z, 0.f); v.w = fmaxf(v.w, 0.f);
    return v;
}

__global__ __launch_bounds__(256) void mlp_kernel(
        const float* __restrict__ z,
        const float* __restrict__ W1, const float* __restrict__ b1,
        const float* __restrict__ W2, const float* __restrict__ b2,
        ushort16* __restrict__ h_out, int N) {
    __shared__ __align__(16) float tile[32][HDIM];
    const int tid = threadIdx.x;
    const int row0 = blockIdx.x * 32;

#pragma unroll
    for (int i = 0; i < 4; ++i) {
        int idx = tid + i * 256;
        int r = idx >> 5, c4 = idx & 31;
        float4 v = make_float4(0.f, 0.f, 0.f, 0.f);
        if (row0 + r < N) v = *(const float4*)(z + (size_t)(row0 + r) * HDIM + c4 * 4);
        *(float4*)(&tile[r][c4 * 4]) = v;
    }
    __syncthreads();

    const int rg = tid >> 5, cg = tid & 31;
    const int r0 = rg * 4, c0 = cg * 4;

    float4 a0, a1, a2, a3;
    {
        float4 bb = *(const float4*)(b1 + c0);
        a0 = a1 = a2 = a3 = bb;
    }
    for (int k = 0; k < HDIM; k += 4) {
        float4 z0 = *(const float4*)(&tile[r0 + 0][k]);
        float4 z1 = *(const float4*)(&tile[r0 + 1][k]);
        float4 z2 = *(const float4*)(&tile[r0 + 2][k]);
        float4 z3 = *(const float4*)(&tile[r0 + 3][k]);
        float4 w0 = *(const float4*)(W1 + (size_t)(k + 0) * HDIM + c0);
        float4 w1 = *(const float4*)(W1 + (size_t)(k + 1) * HDIM + c0);
        float4 w2 = *(const float4*)(W1 + (size_t)(k + 2) * HDIM + c0);
        float4 w3 = *(const float4*)(W1 + (size_t)(k + 3) * HDIM + c0);
        fma4(a0, z0, w0, w1, w2, w3);
        fma4(a1, z1, w0, w1, w2, w3);
        fma4(a2, z2, w0, w1, w2, w3);
        fma4(a3, z3, w0, w1, w2, w3);
    }
    a0 = relu4(a0); a1 = relu4(a1); a2 = relu4(a2); a3 = relu4(a3);
    __syncthreads();
    *(float4*)(&tile[r0 + 0][c0]) = a0;
    *(float4*)(&tile[r0 + 1][c0]) = a1;
    *(float4*)(&tile[r0 + 2][c0]) = a2;
    *(float4*)(&tile[r0 + 3][c0]) = a3;
    __syncthreads();

    {
        float4 bb = *(const float4*)(b2 + c0);
        a0 = a1 = a2 = a3 = bb;
    }
    for (int k = 0; k < HDIM; k += 4) {
        float4 z0 = *(const float4*)(&tile[r0 + 0][k]);
        float4 z1 = *(const float4*)(&tile[r0 + 1][k]);
        float4 z2 = *(const float4*)(&tile[r0 + 2][k]);
        float4 z3 = *(const float4*)(&tile[r0 + 3][k]);
        float4 w0 = *(const float4*)(W2 + (size_t)(k + 0) * HDIM + c0);
        float4 w1 = *(const float4*)(W2 + (size_t)(k + 1) * HDIM + c0);
        float4 w2 = *(const float4*)(W2 + (size_t)(k + 2) * HDIM + c0);
        float4 w3 = *(const float4*)(W2 + (size_t)(k + 3) * HDIM + c0);
        fma4(a0, z0, w0, w1, w2, w3);
        fma4(a1, z1, w0, w1, w2, w3);
        fma4(a2, z2, w0, w1, w2, w3);
        fma4(a3, z3, w0, w1, w2, w3);
    }
    a0 = relu4(a0); a1 = relu4(a1); a2 = relu4(a2); a3 = relu4(a3);
#pragma unroll
    for (int r = 0; r < 4; ++r) {
        if (row0 + r0 + r < N) {
            float4 v = (r == 0) ? a0 : (r == 1) ? a1 : (r == 2) ? a2 : a3;
            ushort4 u;
            u.x = f2bf(v.x); u.y = f2bf(v.y); u.z = f2bf(v.z); u.w = f2bf(v.w);
            *(ushort4*)(h_out + (size_t)(row0 + r0 + r) * HDIM + c0) = u;
        }
    }
}

// ---------------- output projection (reads bf16 h) ----------------
__global__ void out_kernel(const uint32* __restrict__ hq, const float* __restrict__ Wout,
                           const float* __restrict__ bout, float* __restrict__ out, int N) {
    int idx = blockIdx.x * 256 + threadIdx.x;
    int n = idx >> 4, pe = idx & 15;
    if (n >= N) return;
    float acc = bout[pe];
#pragma unroll 8
    for (int k2 = 0; k2 < 64; ++k2) {
        uint32 g = hq[(size_t)n * 64 + k2];
        acc = fmaf(bflo(g), Wout[(2 * k2) * 16 + pe], acc);
        acc = fmaf(bfhi(g), Wout[(2 * k2 + 1) * 16 + pe], acc);
    }
    out[(size_t)n * 16 + pe] = acc;
}

extern "C" void kernel_launch(void* const* d_in, const int* in_sizes, int n_in,
                              void* d_out, int out_size, void* d_ws, size_t ws_size,
                              hipStream_t stream) {
    const int*   x_type     = (const int*)  d_in[0];
    const float* x_feat     = (const float*)d_in[1];
    const int*   edge_index = (const int*)  d_in[2];
    const float* edge_attr  = (const float*)d_in[3];
    const float* type_embed = (const float*)d_in[4];
    const float* featW      = (const float*)d_in[5];
    const float* featb      = (const float*)d_in[6];
    const float* edgeW      = (const float*)d_in[7];
    const float* edgeb      = (const float*)d_in[8];
    const float* W1         = (const float*)d_in[9];
    const float* b1         = (const float*)d_in[10];
    const float* W2         = (const float*)d_in[11];
    const float* b2         = (const float*)d_in[12];
    const float* eps        = (const float*)d_in[13];
    const float* Wout       = (const float*)d_in[14];
    const float* bout       = (const float*)d_in[15];

    const int N = in_sizes[0];
    const int E = in_sizes[2] / 2;
    const int L = in_sizes[13];

    const int* srcIdx = edge_index;
    const int* dstIdx = edge_index + E;

    auto align256 = [](size_t x) { return (x + 255) & ~(size_t)255; };
    char* p = (char*)d_ws;
    ushort16* h_buf  = (ushort16*)p;           p += align256((size_t)N * HDIM * 2);
    float* z_buf     = (float*)p;              p += align256((size_t)N * HDIM * 4);
    int*   deg       = (int*)p;                p += align256((size_t)N * 4);
    int*   row_ptr   = (int*)p;                p += align256((size_t)(N + 1) * 4);
    int*   fill_ptr  = (int*)p;                p += align256((size_t)N * 4);
    int*   adj_src   = (int*)p;                p += align256((size_t)E * 4);
    float4* adj_ea   = (float4*)p;             p += align256((size_t)E * 16);
    int*   partials  = (int*)p;                p += align256(512 * 4);
    int*   offsets   = (int*)p;                p += align256(512 * 4);
    (void)ws_size;

    const int nb = (N + 255) / 256;   // 196 <= 256

    hipMemsetAsync(deg, 0, (size_t)N * 4, stream);
    count_kernel<<<(E + 255) / 256, 256, 0, stream>>>(dstIdx, deg, E);
    partial_kernel<<<nb, 256, 0, stream>>>(deg, partials, N);
    scan_partials_kernel<<<1, 256, 0, stream>>>(partials, offsets, nb, row_ptr, N, E);
    scatter_scan_kernel<<<nb, 256, 0, stream>>>(deg, offsets, row_ptr, fill_ptr, N);
    fill_kernel<<<(E + 255) / 256, 256, 0, stream>>>(srcIdx, dstIdx, edge_attr,
                                                     fill_ptr, adj_src, adj_ea, E);

    embed_kernel<<<((size_t)N * HDIM + 255) / 256, 256, 0, stream>>>(
        x_type, x_feat, type_embed, featW, featb, h_buf, N);

    for (int l = 0; l < L; ++l) {
        agg_kernel<<<(N + 3) / 4, 256, 0, stream>>>(
            (const uint32*)h_buf, row_ptr, adj_src, adj_ea, edgeW, edgeb, eps, l, z_buf, N);
        mlp_kernel<<<(N + 31) / 32, 256, 0, stream>>>(
            z_buf, W1 + (size_t)l * HDIM * HDIM, b1 + (size_t)l * HDIM,
            W2 + (size_t)l * HDIM * HDIM, b2 + (size_t)l * HDIM, h_buf, N);
    }

    out_kernel<<<((size_t)N * 16 + 255) / 256, 256, 0, stream>>>(
        (const uint32*)h_buf, Wout, bout, (float*)d_out, N);
}

// Round 4
// 411.485 us; speedup vs baseline: 2.1515x; 1.1456x over previous
//
#include <hip/hip_runtime.h>
#include <hip/hip_bf16.h>

// ---------------------------------------------------------------------------
// EncoderGNN: 3-layer GINE encoder, N=50000, E=800000, H=128.
// Round 4: MLP moved to bf16 MFMA (mfma_f32_16x16x32_bf16), z stored bf16,
// weights pre-transposed+bf16 once per call. agg = 1 wave/node bf16x2
// gathers unroll x4. 3-phase coalesced scan CSR. No float atomics.
// ---------------------------------------------------------------------------

#define HDIM 128

typedef unsigned int uint32;
typedef unsigned short ushort16;
typedef __attribute__((ext_vector_type(8))) short short8;
typedef __attribute__((ext_vector_type(4))) float f32x4;

__device__ __forceinline__ ushort16 f2bf(float f) {
    uint32 u = __float_as_uint(f);
    u += 0x7fff + ((u >> 16) & 1);      // round-to-nearest-even
    return (ushort16)(u >> 16);
}
__device__ __forceinline__ float bflo(uint32 g) { return __uint_as_float(g << 16); }
__device__ __forceinline__ float bfhi(uint32 g) { return __uint_as_float(g & 0xffff0000u); }

// ---------------- CSR build ----------------
__global__ void count_kernel(const int* __restrict__ dstIdx, int* __restrict__ deg, int E) {
    int e = blockIdx.x * blockDim.x + threadIdx.x;
    if (e < E) atomicAdd(&deg[dstIdx[e]], 1);
}

__global__ __launch_bounds__(256) void partial_kernel(const int* __restrict__ deg,
                                                      int* __restrict__ partials, int N) {
    __shared__ int red[256];
    int i = blockIdx.x * 256 + threadIdx.x;
    red[threadIdx.x] = (i < N) ? deg[i] : 0;
    __syncthreads();
#pragma unroll
    for (int off = 128; off > 0; off >>= 1) {
        if (threadIdx.x < off) red[threadIdx.x] += red[threadIdx.x + off];
        __syncthreads();
    }
    if (threadIdx.x == 0) partials[blockIdx.x] = red[0];
}

__global__ __launch_bounds__(256) void scan_partials_kernel(const int* __restrict__ partials,
                                                            int* __restrict__ offsets,
                                                            int nb, int* __restrict__ row_ptr,
                                                            int N, int E) {
    __shared__ int buf[256];
    int tid = threadIdx.x;
    buf[tid] = (tid < nb) ? partials[tid] : 0;
    __syncthreads();
#pragma unroll
    for (int off = 1; off < 256; off <<= 1) {
        int v = (tid >= off) ? buf[tid - off] : 0;
        __syncthreads();
        buf[tid] += v;
        __syncthreads();
    }
    if (tid < nb) offsets[tid] = buf[tid] - partials[tid];   // exclusive
    if (tid == 0) row_ptr[N] = E;
}

__global__ __launch_bounds__(256) void scatter_scan_kernel(const int* __restrict__ deg,
                                                           const int* __restrict__ offsets,
                                                           int* __restrict__ row_ptr,
                                                           int* __restrict__ fill_ptr, int N) {
    __shared__ int buf[256];
    int tid = threadIdx.x;
    int i = blockIdx.x * 256 + tid;
    int v = (i < N) ? deg[i] : 0;
    buf[tid] = v;
    __syncthreads();
#pragma unroll
    for (int off = 1; off < 256; off <<= 1) {
        int t = (tid >= off) ? buf[tid - off] : 0;
        __syncthreads();
        buf[tid] += t;
        __syncthreads();
    }
    if (i < N) {
        int excl = buf[tid] - v + offsets[blockIdx.x];
        row_ptr[i]  = excl;
        fill_ptr[i] = excl;
    }
}

__global__ void fill_kernel(const int* __restrict__ srcIdx, const int* __restrict__ dstIdx,
                            const float* __restrict__ edge_attr,
                            int* __restrict__ fill_ptr,
                            int* __restrict__ adj_src, float4* __restrict__ adj_ea, int E) {
    int e = blockIdx.x * blockDim.x + threadIdx.x;
    if (e < E) {
        int d = dstIdx[e];
        int pos = atomicAdd(&fill_ptr[d], 1);
        adj_src[pos] = srcIdx[e];
        adj_ea[pos]  = *(const float4*)(edge_attr + (size_t)e * 4);
    }
}

// ---------------- weight prep: bf16 + transpose (once per call) ----------------
// Wb{1,2}t[l][n][k] = W{1,2}[l][k][n] as bf16.
__global__ void prep_weights(const float* __restrict__ W1, const float* __restrict__ W2,
                             ushort16* __restrict__ Wb1t, ushort16* __restrict__ Wb2t, int total) {
    int idx = blockIdx.x * 256 + threadIdx.x;
    if (idx >= total) return;
    int l = idx >> 14;
    int rem = idx & 16383;
    int n = rem >> 7, k = rem & 127;
    size_t src = (size_t)l * 16384 + (size_t)k * 128 + n;
    size_t dst = (size_t)l * 16384 + (size_t)n * 128 + k;
    Wb1t[dst] = f2bf(W1[src]);
    Wb2t[dst] = f2bf(W2[src]);
}

// ---------------- node embedding (writes bf16 h) ----------------
__global__ void embed_kernel(const int* __restrict__ x_type, const float* __restrict__ x_feat,
                             const float* __restrict__ type_embed, const float* __restrict__ featW,
                             const float* __restrict__ featb, ushort16* __restrict__ h, int N) {
    int idx = blockIdx.x * 256 + threadIdx.x;
    int n = idx >> 7, c = idx & 127;
    if (n >= N) return;
    int t = x_type[n];
    float acc = type_embed[(size_t)t * HDIM + c] + featb[c];
#pragma unroll
    for (int k = 0; k < 7; ++k)
        acc = fmaf(x_feat[(size_t)n * 7 + k], featW[(size_t)k * HDIM + c], acc);
    h[(size_t)n * HDIM + c] = f2bf(acc);
}

// ---------------- aggregation: 1 wave/node, lane = 2 channels, writes bf16 z --------
__global__ __launch_bounds__(256) void agg_kernel(
        const uint32* __restrict__ hq,       // [N][64] packed bf16x2
        const int* __restrict__ row_ptr,
        const int* __restrict__ adj_src, const float4* __restrict__ adj_ea,
        const float* __restrict__ edgeW, const float* __restrict__ edgeb,
        const float* __restrict__ eps, int l, uint32* __restrict__ zq, int N) {
    const int node = blockIdx.x * 4 + (threadIdx.x >> 6);
    const int lane = threadIdx.x & 63;
    if (node >= N) return;
    const int c0 = 2 * lane;
    const float w0l = edgeW[c0],       w0h = edgeW[c0 + 1];
    const float w1l = edgeW[128 + c0], w1h = edgeW[128 + c0 + 1];
    const float w2l = edgeW[256 + c0], w2h = edgeW[256 + c0 + 1];
    const float w3l = edgeW[384 + c0], w3h = edgeW[384 + c0 + 1];
    const float ebl = edgeb[c0],       ebh = edgeb[c0 + 1];

    const int beg = row_ptr[node], end = row_ptr[node + 1];
    float acc0 = 0.f, acc1 = 0.f;

    int i = beg;
    for (; i + 4 <= end; i += 4) {
        int s0 = adj_src[i], s1 = adj_src[i + 1], s2 = adj_src[i + 2], s3 = adj_src[i + 3];
        float4 ea0 = adj_ea[i], ea1 = adj_ea[i + 1], ea2 = adj_ea[i + 2], ea3 = adj_ea[i + 3];
        uint32 g0 = hq[(size_t)s0 * 64 + lane];
        uint32 g1 = hq[(size_t)s1 * 64 + lane];
        uint32 g2 = hq[(size_t)s2 * 64 + lane];
        uint32 g3 = hq[(size_t)s3 * 64 + lane];
        float e0l = fmaf(ea0.x, w0l, fmaf(ea0.y, w1l, fmaf(ea0.z, w2l, fmaf(ea0.w, w3l, ebl))));
        float e0h = fmaf(ea0.x, w0h, fmaf(ea0.y, w1h, fmaf(ea0.z, w2h, fmaf(ea0.w, w3h, ebh))));
        float e1l = fmaf(ea1.x, w0l, fmaf(ea1.y, w1l, fmaf(ea1.z, w2l, fmaf(ea1.w, w3l, ebl))));
        float e1h = fmaf(ea1.x, w0h, fmaf(ea1.y, w1h, fmaf(ea1.z, w2h, fmaf(ea1.w, w3h, ebh))));
        float e2l = fmaf(ea2.x, w0l, fmaf(ea2.y, w1l, fmaf(ea2.z, w2l, fmaf(ea2.w, w3l, ebl))));
        float e2h = fmaf(ea2.x, w0h, fmaf(ea2.y, w1h, fmaf(ea2.z, w2h, fmaf(ea2.w, w3h, ebh))));
        float e3l = fmaf(ea3.x, w0l, fmaf(ea3.y, w1l, fmaf(ea3.z, w2l, fmaf(ea3.w, w3l, ebl))));
        float e3h = fmaf(ea3.x, w0h, fmaf(ea3.y, w1h, fmaf(ea3.z, w2h, fmaf(ea3.w, w3h, ebh))));
        acc0 += fmaxf(bflo(g0) + e0l, 0.f);  acc1 += fmaxf(bfhi(g0) + e0h, 0.f);
        acc0 += fmaxf(bflo(g1) + e1l, 0.f);  acc1 += fmaxf(bfhi(g1) + e1h, 0.f);
        acc0 += fmaxf(bflo(g2) + e2l, 0.f);  acc1 += fmaxf(bfhi(g2) + e2h, 0.f);
        acc0 += fmaxf(bflo(g3) + e3l, 0.f);  acc1 += fmaxf(bfhi(g3) + e3h, 0.f);
    }
    for (; i < end; ++i) {
        int s = adj_src[i];
        float4 ea = adj_ea[i];
        uint32 g = hq[(size_t)s * 64 + lane];
        float el = fmaf(ea.x, w0l, fmaf(ea.y, w1l, fmaf(ea.z, w2l, fmaf(ea.w, w3l, ebl))));
        float eh = fmaf(ea.x, w0h, fmaf(ea.y, w1h, fmaf(ea.z, w2h, fmaf(ea.w, w3h, ebh))));
        acc0 += fmaxf(bflo(g) + el, 0.f);
        acc1 += fmaxf(bfhi(g) + eh, 0.f);
    }

    const float ep = 1.0f + eps[l];
    uint32 gs = hq[(size_t)node * 64 + lane];
    float zl = fmaf(ep, bflo(gs), acc0);
    float zh = fmaf(ep, bfhi(gs), acc1);
    zq[(size_t)node * 64 + lane] = ((uint32)f2bf(zh) << 16) | (uint32)f2bf(zl);
}

// ---------------- MFMA MLP: h = relu(relu(z@W1+b1)@W2+b2), bf16 in/out ----------------
// Block: 256 threads = 4 waves, 64 rows. Wave w owns rows [w*16, w*16+16).
// Fragment layouts (gfx950 16x16x32, m89-verified C/D):
//   A: lane l -> row l&15,  k = 8*(l>>4)+j  (short8, contiguous 16B)
//   B: lane l -> col l&15,  k = 8*(l>>4)+j  (from transposed W, contiguous 16B)
//   D: lane l, reg r -> row (l>>4)*4+r, col l&15
#define T_STRIDE 136   // shorts; 272B rows -> 16B aligned, ~2-way banks
__global__ __launch_bounds__(256) void mlp_mfma(
        const ushort16* __restrict__ zq,     // [N][128] bf16
        const ushort16* __restrict__ Wb1t,   // [128 n][128 k] bf16
        const float* __restrict__ b1,
        const ushort16* __restrict__ Wb2t,
        const float* __restrict__ b2,
        ushort16* __restrict__ h_out, int N) {
    __shared__ ushort16 t_lds[64 * T_STRIDE];
    const int tid = threadIdx.x;
    const int w = tid >> 6, lane = tid & 63;
    const int c = lane & 15, g = lane >> 4;
    const int wrow0 = blockIdx.x * 64 + w * 16;

    // ---- GEMM1: t = relu(z @ W1 + b1) ----
    const ushort16* zrow = zq + (size_t)(wrow0 + c) * HDIM + g * 8;
    short8 a[4];
#pragma unroll
    for (int kk = 0; kk < 4; ++kk)
        a[kk] = *(const short8*)(zrow + kk * 32);

    f32x4 acc[8];
#pragma unroll
    for (int n = 0; n < 8; ++n) {
        float bv = b1[n * 16 + c];
        acc[n] = (f32x4){bv, bv, bv, bv};
    }
#pragma unroll
    for (int kk = 0; kk < 4; ++kk) {
#pragma unroll
        for (int n = 0; n < 8; ++n) {
            short8 b = *(const short8*)(Wb1t + (size_t)(n * 16 + c) * HDIM + kk * 32 + g * 8);
            acc[n] = __builtin_amdgcn_mfma_f32_16x16x32_bf16(a[kk], b, acc[n], 0, 0, 0);
        }
    }
    const int lrow0 = w * 16 + g * 4;
#pragma unroll
    for (int n = 0; n < 8; ++n) {
#pragma unroll
        for (int r = 0; r < 4; ++r) {
            float v = fmaxf(acc[n][r], 0.f);
            t_lds[(lrow0 + r) * T_STRIDE + n * 16 + c] = f2bf(v);
        }
    }
    __syncthreads();

    // ---- GEMM2: h = relu(t @ W2 + b2) ----
    short8 a2[4];
#pragma unroll
    for (int kk = 0; kk < 4; ++kk)
        a2[kk] = *(const short8*)(&t_lds[(w * 16 + c) * T_STRIDE + kk * 32 + g * 8]);

    f32x4 acc2[8];
#pragma unroll
    for (int n = 0; n < 8; ++n) {
        float bv = b2[n * 16 + c];
        acc2[n] = (f32x4){bv, bv, bv, bv};
    }
#pragma unroll
    for (int kk = 0; kk < 4; ++kk) {
#pragma unroll
        for (int n = 0; n < 8; ++n) {
            short8 b = *(const short8*)(Wb2t + (size_t)(n * 16 + c) * HDIM + kk * 32 + g * 8);
            acc2[n] = __builtin_amdgcn_mfma_f32_16x16x32_bf16(a2[kk], b, acc2[n], 0, 0, 0);
        }
    }
#pragma unroll
    for (int n = 0; n < 8; ++n) {
#pragma unroll
        for (int r = 0; r < 4; ++r) {
            int row = wrow0 + g * 4 + r;
            if (row < N) {
                float v = fmaxf(acc2[n][r], 0.f);
                h_out[(size_t)row * HDIM + n * 16 + c] = f2bf(v);
            }
        }
    }
}

// ---------------- output projection (reads bf16 h) ----------------
__global__ void out_kernel(const uint32* __restrict__ hq, const float* __restrict__ Wout,
                           const float* __restrict__ bout, float* __restrict__ out, int N) {
    int idx = blockIdx.x * 256 + threadIdx.x;
    int n = idx >> 4, pe = idx & 15;
    if (n >= N) return;
    float acc = bout[pe];
#pragma unroll 8
    for (int k2 = 0; k2 < 64; ++k2) {
        uint32 g = hq[(size_t)n * 64 + k2];
        acc = fmaf(bflo(g), Wout[(2 * k2) * 16 + pe], acc);
        acc = fmaf(bfhi(g), Wout[(2 * k2 + 1) * 16 + pe], acc);
    }
    out[(size_t)n * 16 + pe] = acc;
}

extern "C" void kernel_launch(void* const* d_in, const int* in_sizes, int n_in,
                              void* d_out, int out_size, void* d_ws, size_t ws_size,
                              hipStream_t stream) {
    const int*   x_type     = (const int*)  d_in[0];
    const float* x_feat     = (const float*)d_in[1];
    const int*   edge_index = (const int*)  d_in[2];
    const float* edge_attr  = (const float*)d_in[3];
    const float* type_embed = (const float*)d_in[4];
    const float* featW      = (const float*)d_in[5];
    const float* featb      = (const float*)d_in[6];
    const float* edgeW      = (const float*)d_in[7];
    const float* edgeb      = (const float*)d_in[8];
    const float* W1         = (const float*)d_in[9];
    const float* b1         = (const float*)d_in[10];
    const float* W2         = (const float*)d_in[11];
    const float* b2         = (const float*)d_in[12];
    const float* eps        = (const float*)d_in[13];
    const float* Wout       = (const float*)d_in[14];
    const float* bout       = (const float*)d_in[15];

    const int N = in_sizes[0];
    const int E = in_sizes[2] / 2;
    const int L = in_sizes[13];

    const int* srcIdx = edge_index;
    const int* dstIdx = edge_index + E;

    auto align256 = [](size_t x) { return (x + 255) & ~(size_t)255; };
    char* p = (char*)d_ws;
    ushort16* h_buf  = (ushort16*)p;           p += align256((size_t)N * HDIM * 2);
    ushort16* z_buf  = (ushort16*)p;           p += align256((size_t)N * HDIM * 2);
    int*   deg       = (int*)p;                p += align256((size_t)N * 4);
    int*   row_ptr   = (int*)p;                p += align256((size_t)(N + 1) * 4);
    int*   fill_ptr  = (int*)p;                p += align256((size_t)N * 4);
    int*   adj_src   = (int*)p;                p += align256((size_t)E * 4);
    float4* adj_ea   = (float4*)p;             p += align256((size_t)E * 16);
    int*   partials  = (int*)p;                p += align256(512 * 4);
    int*   offsets   = (int*)p;                p += align256(512 * 4);
    ushort16* Wb1t   = (ushort16*)p;           p += align256((size_t)L * HDIM * HDIM * 2);
    ushort16* Wb2t   = (ushort16*)p;           p += align256((size_t)L * HDIM * HDIM * 2);
    (void)ws_size;

    const int nb = (N + 255) / 256;   // 196 <= 256

    hipMemsetAsync(deg, 0, (size_t)N * 4, stream);
    count_kernel<<<(E + 255) / 256, 256, 0, stream>>>(dstIdx, deg, E);
    partial_kernel<<<nb, 256, 0, stream>>>(deg, partials, N);
    scan_partials_kernel<<<1, 256, 0, stream>>>(partials, offsets, nb, row_ptr, N, E);
    scatter_scan_kernel<<<nb, 256, 0, stream>>>(deg, offsets, row_ptr, fill_ptr, N);
    fill_kernel<<<(E + 255) / 256, 256, 0, stream>>>(srcIdx, dstIdx, edge_attr,
                                                     fill_ptr, adj_src, adj_ea, E);

    const int wtotal = L * HDIM * HDIM;
    prep_weights<<<(wtotal + 255) / 256, 256, 0, stream>>>(W1, W2, Wb1t, Wb2t, wtotal);

    embed_kernel<<<((size_t)N * HDIM + 255) / 256, 256, 0, stream>>>(
        x_type, x_feat, type_embed, featW, featb, h_buf, N);

    for (int l = 0; l < L; ++l) {
        agg_kernel<<<(N + 3) / 4, 256, 0, stream>>>(
            (const uint32*)h_buf, row_ptr, adj_src, adj_ea, edgeW, edgeb, eps, l,
            (uint32*)z_buf, N);
        mlp_mfma<<<(N + 63) / 64, 256, 0, stream>>>(
            z_buf, Wb1t + (size_t)l * HDIM * HDIM, b1 + (size_t)l * HDIM,
            Wb2t + (size_t)l * HDIM * HDIM, b2 + (size_t)l * HDIM, h_buf, N);
    }

    out_kernel<<<((size_t)N * 16 + 255) / 256, 256, 0, stream>>>(
        (const uint32*)h_buf, Wout, bout, (float*)d_out, N);
}

// Round 5
// 397.018 us; speedup vs baseline: 2.2299x; 1.0364x over previous
//
#include <hip/hip_runtime.h>
#include <hip/hip_bf16.h>

// ---------------------------------------------------------------------------
// EncoderGNN: 3-layer GINE encoder, N=50000, E=800000, H=128.
// Round 5: (a) fill writes ONE 16B record/edge {src, ea as bf16x4} -> ~half
// the scatter line-traffic; (b) agg 128-thd blocks (tail balance) reading the
// 16B records; (c) MFMA MLP operand-swapped (t^T = W1^T@z^T, h^T = W2^T@t^T)
// so epilogue stores are packed ushort4 (8x8B instead of 32x2B).
// ---------------------------------------------------------------------------

#define HDIM 128

typedef unsigned int uint32;
typedef unsigned short ushort16;
typedef __attribute__((ext_vector_type(8))) short short8;
typedef __attribute__((ext_vector_type(4))) float f32x4;

__device__ __forceinline__ ushort16 f2bf(float f) {
    uint32 u = __float_as_uint(f);
    u += 0x7fff + ((u >> 16) & 1);      // round-to-nearest-even
    return (ushort16)(u >> 16);
}
__device__ __forceinline__ float bflo(uint32 g) { return __uint_as_float(g << 16); }
__device__ __forceinline__ float bfhi(uint32 g) { return __uint_as_float(g & 0xffff0000u); }

// ---------------- CSR build ----------------
__global__ void count_kernel(const int* __restrict__ dstIdx, int* __restrict__ deg, int E) {
    int e = blockIdx.x * blockDim.x + threadIdx.x;
    if (e < E) atomicAdd(&deg[dstIdx[e]], 1);
}

__global__ __launch_bounds__(256) void partial_kernel(const int* __restrict__ deg,
                                                      int* __restrict__ partials, int N) {
    __shared__ int red[256];
    int i = blockIdx.x * 256 + threadIdx.x;
    red[threadIdx.x] = (i < N) ? deg[i] : 0;
    __syncthreads();
#pragma unroll
    for (int off = 128; off > 0; off >>= 1) {
        if (threadIdx.x < off) red[threadIdx.x] += red[threadIdx.x + off];
        __syncthreads();
    }
    if (threadIdx.x == 0) partials[blockIdx.x] = red[0];
}

__global__ __launch_bounds__(256) void scan_partials_kernel(const int* __restrict__ partials,
                                                            int* __restrict__ offsets,
                                                            int nb, int* __restrict__ row_ptr,
                                                            int N, int E) {
    __shared__ int buf[256];
    int tid = threadIdx.x;
    buf[tid] = (tid < nb) ? partials[tid] : 0;
    __syncthreads();
#pragma unroll
    for (int off = 1; off < 256; off <<= 1) {
        int v = (tid >= off) ? buf[tid - off] : 0;
        __syncthreads();
        buf[tid] += v;
        __syncthreads();
    }
    if (tid < nb) offsets[tid] = buf[tid] - partials[tid];   // exclusive
    if (tid == 0) row_ptr[N] = E;
}

__global__ __launch_bounds__(256) void scatter_scan_kernel(const int* __restrict__ deg,
                                                           const int* __restrict__ offsets,
                                                           int* __restrict__ row_ptr,
                                                           int* __restrict__ fill_ptr, int N) {
    __shared__ int buf[256];
    int tid = threadIdx.x;
    int i = blockIdx.x * 256 + tid;
    int v = (i < N) ? deg[i] : 0;
    buf[tid] = v;
    __syncthreads();
#pragma unroll
    for (int off = 1; off < 256; off <<= 1) {
        int t = (tid >= off) ? buf[tid - off] : 0;
        __syncthreads();
        buf[tid] += t;
        __syncthreads();
    }
    if (i < N) {
        int excl = buf[tid] - v + offsets[blockIdx.x];
        row_ptr[i]  = excl;
        fill_ptr[i] = excl;
    }
}

// one 16B record per edge: {src, ea01(bf16x2), ea23(bf16x2), 0}
__global__ void fill_kernel(const int* __restrict__ srcIdx, const int* __restrict__ dstIdx,
                            const float* __restrict__ edge_attr,
                            int* __restrict__ fill_ptr, int4* __restrict__ adj, int E) {
    int e = blockIdx.x * blockDim.x + threadIdx.x;
    if (e < E) {
        int d = dstIdx[e];
        int pos = atomicAdd(&fill_ptr[d], 1);
        float4 ea = *(const float4*)(edge_attr + (size_t)e * 4);
        int4 rec;
        rec.x = srcIdx[e];
        rec.y = (int)(((uint32)f2bf(ea.y) << 16) | (uint32)f2bf(ea.x));
        rec.z = (int)(((uint32)f2bf(ea.w) << 16) | (uint32)f2bf(ea.z));
        rec.w = 0;
        adj[pos] = rec;
    }
}

// ---------------- weight prep: bf16 + transpose (once per call) ----------------
__global__ void prep_weights(const float* __restrict__ W1, const float* __restrict__ W2,
                             ushort16* __restrict__ Wb1t, ushort16* __restrict__ Wb2t, int total) {
    int idx = blockIdx.x * 256 + threadIdx.x;
    if (idx >= total) return;
    int l = idx >> 14;
    int rem = idx & 16383;
    int n = rem >> 7, k = rem & 127;
    size_t src = (size_t)l * 16384 + (size_t)k * 128 + n;
    size_t dst = (size_t)l * 16384 + (size_t)n * 128 + k;
    Wb1t[dst] = f2bf(W1[src]);
    Wb2t[dst] = f2bf(W2[src]);
}

// ---------------- node embedding (writes bf16 h) ----------------
__global__ void embed_kernel(const int* __restrict__ x_type, const float* __restrict__ x_feat,
                             const float* __restrict__ type_embed, const float* __restrict__ featW,
                             const float* __restrict__ featb, ushort16* __restrict__ h, int N) {
    int idx = blockIdx.x * 256 + threadIdx.x;
    int n = idx >> 7, c = idx & 127;
    if (n >= N) return;
    int t = x_type[n];
    float acc = type_embed[(size_t)t * HDIM + c] + featb[c];
#pragma unroll
    for (int k = 0; k < 7; ++k)
        acc = fmaf(x_feat[(size_t)n * 7 + k], featW[(size_t)k * HDIM + c], acc);
    h[(size_t)n * HDIM + c] = f2bf(acc);
}

// ---------------- aggregation: 1 wave/node (128-thd blocks), bf16 z out ------------
__global__ __launch_bounds__(128) void agg_kernel(
        const uint32* __restrict__ hq,       // [N][64] packed bf16x2
        const int* __restrict__ row_ptr,
        const int4* __restrict__ adj,        // 16B records
        const float* __restrict__ edgeW, const float* __restrict__ edgeb,
        const float* __restrict__ eps, int l, uint32* __restrict__ zq, int N) {
    const int node = blockIdx.x * 2 + (threadIdx.x >> 6);
    const int lane = threadIdx.x & 63;
    if (node >= N) return;
    const int c0 = 2 * lane;
    const float w0l = edgeW[c0],       w0h = edgeW[c0 + 1];
    const float w1l = edgeW[128 + c0], w1h = edgeW[128 + c0 + 1];
    const float w2l = edgeW[256 + c0], w2h = edgeW[256 + c0 + 1];
    const float w3l = edgeW[384 + c0], w3h = edgeW[384 + c0 + 1];
    const float ebl = edgeb[c0],       ebh = edgeb[c0 + 1];

    const int beg = row_ptr[node], end = row_ptr[node + 1];
    float acc0 = 0.f, acc1 = 0.f;

    int i = beg;
    for (; i + 4 <= end; i += 4) {
        int4 r0 = adj[i], r1 = adj[i + 1], r2 = adj[i + 2], r3 = adj[i + 3];
        uint32 g0 = hq[(size_t)r0.x * 64 + lane];
        uint32 g1 = hq[(size_t)r1.x * 64 + lane];
        uint32 g2 = hq[(size_t)r2.x * 64 + lane];
        uint32 g3 = hq[(size_t)r3.x * 64 + lane];
        float e0l = fmaf(bflo(r0.y), w0l, fmaf(bfhi(r0.y), w1l, fmaf(bflo(r0.z), w2l, fmaf(bfhi(r0.z), w3l, ebl))));
        float e0h = fmaf(bflo(r0.y), w0h, fmaf(bfhi(r0.y), w1h, fmaf(bflo(r0.z), w2h, fmaf(bfhi(r0.z), w3h, ebh))));
        float e1l = fmaf(bflo(r1.y), w0l, fmaf(bfhi(r1.y), w1l, fmaf(bflo(r1.z), w2l, fmaf(bfhi(r1.z), w3l, ebl))));
        float e1h = fmaf(bflo(r1.y), w0h, fmaf(bfhi(r1.y), w1h, fmaf(bflo(r1.z), w2h, fmaf(bfhi(r1.z), w3h, ebh))));
        float e2l = fmaf(bflo(r2.y), w0l, fmaf(bfhi(r2.y), w1l, fmaf(bflo(r2.z), w2l, fmaf(bfhi(r2.z), w3l, ebl))));
        float e2h = fmaf(bflo(r2.y), w0h, fmaf(bfhi(r2.y), w1h, fmaf(bflo(r2.z), w2h, fmaf(bfhi(r2.z), w3h, ebh))));
        float e3l = fmaf(bflo(r3.y), w0l, fmaf(bfhi(r3.y), w1l, fmaf(bflo(r3.z), w2l, fmaf(bfhi(r3.z), w3l, ebl))));
        float e3h = fmaf(bflo(r3.y), w0h, fmaf(bfhi(r3.y), w1h, fmaf(bflo(r3.z), w2h, fmaf(bfhi(r3.z), w3h, ebh))));
        acc0 += fmaxf(bflo(g0) + e0l, 0.f);  acc1 += fmaxf(bfhi(g0) + e0h, 0.f);
        acc0 += fmaxf(bflo(g1) + e1l, 0.f);  acc1 += fmaxf(bfhi(g1) + e1h, 0.f);
        acc0 += fmaxf(bflo(g2) + e2l, 0.f);  acc1 += fmaxf(bfhi(g2) + e2h, 0.f);
        acc0 += fmaxf(bflo(g3) + e3l, 0.f);  acc1 += fmaxf(bfhi(g3) + e3h, 0.f);
    }
    for (; i < end; ++i) {
        int4 r = adj[i];
        uint32 g = hq[(size_t)r.x * 64 + lane];
        float el = fmaf(bflo(r.y), w0l, fmaf(bfhi(r.y), w1l, fmaf(bflo(r.z), w2l, fmaf(bfhi(r.z), w3l, ebl))));
        float eh = fmaf(bflo(r.y), w0h, fmaf(bfhi(r.y), w1h, fmaf(bflo(r.z), w2h, fmaf(bfhi(r.z), w3h, ebh))));
        acc0 += fmaxf(bflo(g) + el, 0.f);
        acc1 += fmaxf(bfhi(g) + eh, 0.f);
    }

    const float ep = 1.0f + eps[l];
    uint32 gs = hq[(size_t)node * 64 + lane];
    float zl = fmaf(ep, bflo(gs), acc0);
    float zh = fmaf(ep, bfhi(gs), acc1);
    zq[(size_t)node * 64 + lane] = ((uint32)f2bf(zh) << 16) | (uint32)f2bf(zl);
}

// ---------------- MFMA MLP, operand-swapped ----------------
// t^T = W1^T @ z^T ; h^T = W2^T @ t^T  (D cols = nodes, D rows = channels)
// A-frag (W*t, layout [n][k]):   lane l -> chan n0+(l&15), k = (l>>4)*8+j  : 16B contig
// B-frag (z^T / t^T):            lane l -> node (l&15),    k = (l>>4)*8+j  : 16B contig
// D:                             lane l -> node (l&15), chans n0+(l>>4)*4+r -> ushort4 store
#define T_STRIDE 136   // shorts; 272B rows: 16B-aligned for b128 reads
__global__ __launch_bounds__(256) void mlp_mfma(
        const ushort16* __restrict__ zq,     // [N64][128] bf16
        const ushort16* __restrict__ Wb1t,   // [128 n][128 k] bf16
        const float* __restrict__ b1,
        const ushort16* __restrict__ Wb2t,
        const float* __restrict__ b2,
        ushort16* __restrict__ h_out, int N) {
    __shared__ ushort16 t_lds[64 * T_STRIDE];
    const int tid = threadIdx.x;
    const int w = tid >> 6, lane = tid & 63;
    const int c = lane & 15, g = lane >> 4;
    const int wrow0 = blockIdx.x * 64 + w * 16;   // node-tile base for this wave

    // ---- GEMM1: t^T = W1^T @ z^T ----
    const ushort16* zrow = zq + (size_t)(wrow0 + c) * HDIM + g * 8;
    short8 bf[4];
#pragma unroll
    for (int kk = 0; kk < 4; ++kk)
        bf[kk] = *(const short8*)(zrow + kk * 32);

    f32x4 acc[8];
#pragma unroll
    for (int n = 0; n < 8; ++n) {
        float4 bb = *(const float4*)(b1 + n * 16 + g * 4);
        acc[n] = (f32x4){bb.x, bb.y, bb.z, bb.w};
    }
#pragma unroll
    for (int kk = 0; kk < 4; ++kk) {
#pragma unroll
        for (int n = 0; n < 8; ++n) {
            short8 af = *(const short8*)(Wb1t + (size_t)(n * 16 + c) * HDIM + kk * 32 + g * 8);
            acc[n] = __builtin_amdgcn_mfma_f32_16x16x32_bf16(af, bf[kk], acc[n], 0, 0, 0);
        }
    }
    // store t[node][chan]: lane -> node w*16+c, chans n*16+g*4..+3 (packed 8B)
#pragma unroll
    for (int n = 0; n < 8; ++n) {
        ushort4 u;
        u.x = f2bf(fmaxf(acc[n][0], 0.f));
        u.y = f2bf(fmaxf(acc[n][1], 0.f));
        u.z = f2bf(fmaxf(acc[n][2], 0.f));
        u.w = f2bf(fmaxf(acc[n][3], 0.f));
        *(ushort4*)(&t_lds[(w * 16 + c) * T_STRIDE + n * 16 + g * 4]) = u;
    }
    __syncthreads();

    // ---- GEMM2: h^T = W2^T @ t^T ----
    short8 bf2[4];
#pragma unroll
    for (int kk = 0; kk < 4; ++kk)
        bf2[kk] = *(const short8*)(&t_lds[(w * 16 + c) * T_STRIDE + kk * 32 + g * 8]);

    f32x4 acc2[8];
#pragma unroll
    for (int n = 0; n < 8; ++n) {
        float4 bb = *(const float4*)(b2 + n * 16 + g * 4);
        acc2[n] = (f32x4){bb.x, bb.y, bb.z, bb.w};
    }
#pragma unroll
    for (int kk = 0; kk < 4; ++kk) {
#pragma unroll
        for (int n = 0; n < 8; ++n) {
            short8 af = *(const short8*)(Wb2t + (size_t)(n * 16 + c) * HDIM + kk * 32 + g * 8);
            acc2[n] = __builtin_amdgcn_mfma_f32_16x16x32_bf16(af, bf2[kk], acc2[n], 0, 0, 0);
        }
    }
    if (wrow0 + c < N) {
#pragma unroll
        for (int n = 0; n < 8; ++n) {
            ushort4 u;
            u.x = f2bf(fmaxf(acc2[n][0], 0.f));
            u.y = f2bf(fmaxf(acc2[n][1], 0.f));
            u.z = f2bf(fmaxf(acc2[n][2], 0.f));
            u.w = f2bf(fmaxf(acc2[n][3], 0.f));
            *(ushort4*)(h_out + (size_t)(wrow0 + c) * HDIM + n * 16 + g * 4) = u;
        }
    }
}

// ---------------- output projection (reads bf16 h) ----------------
__global__ void out_kernel(const uint32* __restrict__ hq, const float* __restrict__ Wout,
                           const float* __restrict__ bout, float* __restrict__ out, int N) {
    int idx = blockIdx.x * 256 + threadIdx.x;
    int n = idx >> 4, pe = idx & 15;
    if (n >= N) return;
    float acc = bout[pe];
#pragma unroll 8
    for (int k2 = 0; k2 < 64; ++k2) {
        uint32 g = hq[(size_t)n * 64 + k2];
        acc = fmaf(bflo(g), Wout[(2 * k2) * 16 + pe], acc);
        acc = fmaf(bfhi(g), Wout[(2 * k2 + 1) * 16 + pe], acc);
    }
    out[(size_t)n * 16 + pe] = acc;
}

extern "C" void kernel_launch(void* const* d_in, const int* in_sizes, int n_in,
                              void* d_out, int out_size, void* d_ws, size_t ws_size,
                              hipStream_t stream) {
    const int*   x_type     = (const int*)  d_in[0];
    const float* x_feat     = (const float*)d_in[1];
    const int*   edge_index = (const int*)  d_in[2];
    const float* edge_attr  = (const float*)d_in[3];
    const float* type_embed = (const float*)d_in[4];
    const float* featW      = (const float*)d_in[5];
    const float* featb      = (const float*)d_in[6];
    const float* edgeW      = (const float*)d_in[7];
    const float* edgeb      = (const float*)d_in[8];
    const float* W1         = (const float*)d_in[9];
    const float* b1         = (const float*)d_in[10];
    const float* W2         = (const float*)d_in[11];
    const float* b2         = (const float*)d_in[12];
    const float* eps        = (const float*)d_in[13];
    const float* Wout       = (const float*)d_in[14];
    const float* bout       = (const float*)d_in[15];

    const int N = in_sizes[0];
    const int E = in_sizes[2] / 2;
    const int L = in_sizes[13];
    const int N64 = (N + 63) & ~63;     // pad node buffers so MFMA tiles read in-bounds

    const int* srcIdx = edge_index;
    const int* dstIdx = edge_index + E;

    auto align256 = [](size_t x) { return (x + 255) & ~(size_t)255; };
    char* p = (char*)d_ws;
    ushort16* h_buf  = (ushort16*)p;           p += align256((size_t)N64 * HDIM * 2);
    ushort16* z_buf  = (ushort16*)p;           p += align256((size_t)N64 * HDIM * 2);
    int*   deg       = (int*)p;                p += align256((size_t)N * 4);
    int*   row_ptr   = (int*)p;                p += align256((size_t)(N + 1) * 4);
    int*   fill_ptr  = (int*)p;                p += align256((size_t)N * 4);
    int4*  adj       = (int4*)p;               p += align256((size_t)E * 16);
    int*   partials  = (int*)p;                p += align256(512 * 4);
    int*   offsets   = (int*)p;                p += align256(512 * 4);
    ushort16* Wb1t   = (ushort16*)p;           p += align256((size_t)L * HDIM * HDIM * 2);
    ushort16* Wb2t   = (ushort16*)p;           p += align256((size_t)L * HDIM * HDIM * 2);
    (void)ws_size;

    const int nb = (N + 255) / 256;   // 196 <= 256

    hipMemsetAsync(deg, 0, (size_t)N * 4, stream);
    count_kernel<<<(E + 255) / 256, 256, 0, stream>>>(dstIdx, deg, E);
    partial_kernel<<<nb, 256, 0, stream>>>(deg, partials, N);
    scan_partials_kernel<<<1, 256, 0, stream>>>(partials, offsets, nb, row_ptr, N, E);
    scatter_scan_kernel<<<nb, 256, 0, stream>>>(deg, offsets, row_ptr, fill_ptr, N);
    fill_kernel<<<(E + 255) / 256, 256, 0, stream>>>(srcIdx, dstIdx, edge_attr,
                                                     fill_ptr, adj, E);

    const int wtotal = L * HDIM * HDIM;
    prep_weights<<<(wtotal + 255) / 256, 256, 0, stream>>>(W1, W2, Wb1t, Wb2t, wtotal);

    embed_kernel<<<((size_t)N * HDIM + 255) / 256, 256, 0, stream>>>(
        x_type, x_feat, type_embed, featW, featb, h_buf, N);

    for (int l = 0; l < L; ++l) {
        agg_kernel<<<(N + 1) / 2, 128, 0, stream>>>(
            (const uint32*)h_buf, row_ptr, adj, edgeW, edgeb, eps, l,
            (uint32*)z_buf, N);
        mlp_mfma<<<N64 / 64, 256, 0, stream>>>(
            z_buf, Wb1t + (size_t)l * HDIM * HDIM, b1 + (size_t)l * HDIM,
            Wb2t + (size_t)l * HDIM * HDIM, b2 + (size_t)l * HDIM, h_buf, N);
    }

    out_kernel<<<((size_t)N * 16 + 255) / 256, 256, 0, stream>>>(
        (const uint32*)h_buf, Wout, bout, (float*)d_out, N);
}

// Round 6
// 360.063 us; speedup vs baseline: 2.4587x; 1.1026x over previous
//
#include <hip/hip_runtime.h>
#include <hip/hip_bf16.h>

// ---------------------------------------------------------------------------
// EncoderGNN: 3-layer GINE encoder, N=50000, E=800000, H=128.
// Round 6: agg scalarized — readfirstlane(beg/end) makes the edge loop
// wave-uniform so adj records load via SMEM (s_load_dwordx4/x16, scalar pipe)
// and gathers take saddr form; channel math packed as f32x2 (v_pk_fma_f32);
// unroll x8 with 2 independent accumulators. Everything else as round 5.
// ---------------------------------------------------------------------------

#define HDIM 128

typedef unsigned int uint32;
typedef unsigned short ushort16;
typedef __attribute__((ext_vector_type(8))) short short8;
typedef __attribute__((ext_vector_type(4))) float f32x4;
typedef __attribute__((ext_vector_type(2))) float f32x2;

__device__ __forceinline__ ushort16 f2bf(float f) {
    uint32 u = __float_as_uint(f);
    u += 0x7fff + ((u >> 16) & 1);      // round-to-nearest-even
    return (ushort16)(u >> 16);
}
__device__ __forceinline__ float bflo(uint32 g) { return __uint_as_float(g << 16); }
__device__ __forceinline__ float bfhi(uint32 g) { return __uint_as_float(g & 0xffff0000u); }

// ---------------- CSR build ----------------
__global__ void count_kernel(const int* __restrict__ dstIdx, int* __restrict__ deg, int E) {
    int e = blockIdx.x * blockDim.x + threadIdx.x;
    if (e < E) atomicAdd(&deg[dstIdx[e]], 1);
}

__global__ __launch_bounds__(256) void partial_kernel(const int* __restrict__ deg,
                                                      int* __restrict__ partials, int N) {
    __shared__ int red[256];
    int i = blockIdx.x * 256 + threadIdx.x;
    red[threadIdx.x] = (i < N) ? deg[i] : 0;
    __syncthreads();
#pragma unroll
    for (int off = 128; off > 0; off >>= 1) {
        if (threadIdx.x < off) red[threadIdx.x] += red[threadIdx.x + off];
        __syncthreads();
    }
    if (threadIdx.x == 0) partials[blockIdx.x] = red[0];
}

__global__ __launch_bounds__(256) void scan_partials_kernel(const int* __restrict__ partials,
                                                            int* __restrict__ offsets,
                                                            int nb, int* __restrict__ row_ptr,
                                                            int N, int E) {
    __shared__ int buf[256];
    int tid = threadIdx.x;
    buf[tid] = (tid < nb) ? partials[tid] : 0;
    __syncthreads();
#pragma unroll
    for (int off = 1; off < 256; off <<= 1) {
        int v = (tid >= off) ? buf[tid - off] : 0;
        __syncthreads();
        buf[tid] += v;
        __syncthreads();
    }
    if (tid < nb) offsets[tid] = buf[tid] - partials[tid];   // exclusive
    if (tid == 0) row_ptr[N] = E;
}

__global__ __launch_bounds__(256) void scatter_scan_kernel(const int* __restrict__ deg,
                                                           const int* __restrict__ offsets,
                                                           int* __restrict__ row_ptr,
                                                           int* __restrict__ fill_ptr, int N) {
    __shared__ int buf[256];
    int tid = threadIdx.x;
    int i = blockIdx.x * 256 + tid;
    int v = (i < N) ? deg[i] : 0;
    buf[tid] = v;
    __syncthreads();
#pragma unroll
    for (int off = 1; off < 256; off <<= 1) {
        int t = (tid >= off) ? buf[tid - off] : 0;
        __syncthreads();
        buf[tid] += t;
        __syncthreads();
    }
    if (i < N) {
        int excl = buf[tid] - v + offsets[blockIdx.x];
        row_ptr[i]  = excl;
        fill_ptr[i] = excl;
    }
}

// one 16B record per edge: {src, ea01(bf16x2), ea23(bf16x2), 0}
__global__ void fill_kernel(const int* __restrict__ srcIdx, const int* __restrict__ dstIdx,
                            const float* __restrict__ edge_attr,
                            int* __restrict__ fill_ptr, int4* __restrict__ adj, int E) {
    int e = blockIdx.x * blockDim.x + threadIdx.x;
    if (e < E) {
        int d = dstIdx[e];
        int pos = atomicAdd(&fill_ptr[d], 1);
        float4 ea = *(const float4*)(edge_attr + (size_t)e * 4);
        int4 rec;
        rec.x = srcIdx[e];
        rec.y = (int)(((uint32)f2bf(ea.y) << 16) | (uint32)f2bf(ea.x));
        rec.z = (int)(((uint32)f2bf(ea.w) << 16) | (uint32)f2bf(ea.z));
        rec.w = 0;
        adj[pos] = rec;
    }
}

// ---------------- weight prep: bf16 + transpose (once per call) ----------------
__global__ void prep_weights(const float* __restrict__ W1, const float* __restrict__ W2,
                             ushort16* __restrict__ Wb1t, ushort16* __restrict__ Wb2t, int total) {
    int idx = blockIdx.x * 256 + threadIdx.x;
    if (idx >= total) return;
    int l = idx >> 14;
    int rem = idx & 16383;
    int n = rem >> 7, k = rem & 127;
    size_t src = (size_t)l * 16384 + (size_t)k * 128 + n;
    size_t dst = (size_t)l * 16384 + (size_t)n * 128 + k;
    Wb1t[dst] = f2bf(W1[src]);
    Wb2t[dst] = f2bf(W2[src]);
}

// ---------------- node embedding (writes bf16 h) ----------------
__global__ void embed_kernel(const int* __restrict__ x_type, const float* __restrict__ x_feat,
                             const float* __restrict__ type_embed, const float* __restrict__ featW,
                             const float* __restrict__ featb, ushort16* __restrict__ h, int N) {
    int idx = blockIdx.x * 256 + threadIdx.x;
    int n = idx >> 7, c = idx & 127;
    if (n >= N) return;
    int t = x_type[n];
    float acc = type_embed[(size_t)t * HDIM + c] + featb[c];
#pragma unroll
    for (int k = 0; k < 7; ++k)
        acc = fmaf(x_feat[(size_t)n * 7 + k], featW[(size_t)k * HDIM + c], acc);
    h[(size_t)n * HDIM + c] = f2bf(acc);
}

// ---------------- aggregation: 1 wave/node, scalarized edge loop ----------------
__global__ __launch_bounds__(128) void agg_kernel(
        const uint32* __restrict__ hq,       // [N][64] packed bf16x2
        const int* __restrict__ row_ptr,
        const int4* __restrict__ adj,        // 16B records (uniform per wave)
        const float* __restrict__ edgeW, const float* __restrict__ edgeb,
        const float* __restrict__ eps, int l, uint32* __restrict__ zq, int N) {
    const int node = blockIdx.x * 2 + (threadIdx.x >> 6);
    const int lane = threadIdx.x & 63;
    if (node >= N) return;
    const int c0 = 2 * lane;
    const f32x2 w0 = {edgeW[c0],       edgeW[c0 + 1]};
    const f32x2 w1 = {edgeW[128 + c0], edgeW[128 + c0 + 1]};
    const f32x2 w2 = {edgeW[256 + c0], edgeW[256 + c0 + 1]};
    const f32x2 w3 = {edgeW[384 + c0], edgeW[384 + c0 + 1]};
    const f32x2 eb = {edgeb[c0],       edgeb[c0 + 1]};

    // wave-uniform loop bounds -> SGPR (enables s_load of adj + saddr gathers)
    const int beg = __builtin_amdgcn_readfirstlane(row_ptr[node]);
    const int end = __builtin_amdgcn_readfirstlane(row_ptr[node + 1]);

    // start the self-term load early
    const uint32 gs = hq[(size_t)node * 64 + lane];

    f32x2 accA = {0.f, 0.f}, accB = {0.f, 0.f};

#define EDGE(Q, G, ACC) {                                                     \
        f32x2 e = eb;                                                         \
        e += bflo((uint32)(Q).y) * w0;                                        \
        e += bfhi((uint32)(Q).y) * w1;                                        \
        e += bflo((uint32)(Q).z) * w2;                                        \
        e += bfhi((uint32)(Q).z) * w3;                                        \
        f32x2 m = {bflo(G) + e.x, bfhi(G) + e.y};                             \
        ACC.x += fmaxf(m.x, 0.f);                                             \
        ACC.y += fmaxf(m.y, 0.f);                                             \
    }

    int i = beg;
    for (; i + 8 <= end; i += 8) {
        int4 q0 = adj[i + 0], q1 = adj[i + 1], q2 = adj[i + 2], q3 = adj[i + 3];
        int4 q4 = adj[i + 4], q5 = adj[i + 5], q6 = adj[i + 6], q7 = adj[i + 7];
        uint32 g0 = hq[(size_t)q0.x * 64 + lane];
        uint32 g1 = hq[(size_t)q1.x * 64 + lane];
        uint32 g2 = hq[(size_t)q2.x * 64 + lane];
        uint32 g3 = hq[(size_t)q3.x * 64 + lane];
        uint32 g4 = hq[(size_t)q4.x * 64 + lane];
        uint32 g5 = hq[(size_t)q5.x * 64 + lane];
        uint32 g6 = hq[(size_t)q6.x * 64 + lane];
        uint32 g7 = hq[(size_t)q7.x * 64 + lane];
        EDGE(q0, g0, accA); EDGE(q1, g1, accB);
        EDGE(q2, g2, accA); EDGE(q3, g3, accB);
        EDGE(q4, g4, accA); EDGE(q5, g5, accB);
        EDGE(q6, g6, accA); EDGE(q7, g7, accB);
    }
    for (; i < end; ++i) {
        int4 q = adj[i];
        uint32 g = hq[(size_t)q.x * 64 + lane];
        EDGE(q, g, accA);
    }
#undef EDGE

    const float ep = 1.0f + eps[l];
    float zl = fmaf(ep, bflo(gs), accA.x + accB.x);
    float zh = fmaf(ep, bfhi(gs), accA.y + accB.y);
    zq[(size_t)node * 64 + lane] = ((uint32)f2bf(zh) << 16) | (uint32)f2bf(zl);
}

// ---------------- MFMA MLP, operand-swapped ----------------
#define T_STRIDE 136   // shorts; 272B rows: 16B-aligned for b128 reads
__global__ __launch_bounds__(256) void mlp_mfma(
        const ushort16* __restrict__ zq,     // [N64][128] bf16
        const ushort16* __restrict__ Wb1t,   // [128 n][128 k] bf16
        const float* __restrict__ b1,
        const ushort16* __restrict__ Wb2t,
        const float* __restrict__ b2,
        ushort16* __restrict__ h_out, int N) {
    __shared__ ushort16 t_lds[64 * T_STRIDE];
    const int tid = threadIdx.x;
    const int w = tid >> 6, lane = tid & 63;
    const int c = lane & 15, g = lane >> 4;
    const int wrow0 = blockIdx.x * 64 + w * 16;   // node-tile base for this wave

    // ---- GEMM1: t^T = W1^T @ z^T ----
    const ushort16* zrow = zq + (size_t)(wrow0 + c) * HDIM + g * 8;
    short8 bf[4];
#pragma unroll
    for (int kk = 0; kk < 4; ++kk)
        bf[kk] = *(const short8*)(zrow + kk * 32);

    f32x4 acc[8];
#pragma unroll
    for (int n = 0; n < 8; ++n) {
        float4 bb = *(const float4*)(b1 + n * 16 + g * 4);
        acc[n] = (f32x4){bb.x, bb.y, bb.z, bb.w};
    }
#pragma unroll
    for (int kk = 0; kk < 4; ++kk) {
#pragma unroll
        for (int n = 0; n < 8; ++n) {
            short8 af = *(const short8*)(Wb1t + (size_t)(n * 16 + c) * HDIM + kk * 32 + g * 8);
            acc[n] = __builtin_amdgcn_mfma_f32_16x16x32_bf16(af, bf[kk], acc[n], 0, 0, 0);
        }
    }
#pragma unroll
    for (int n = 0; n < 8; ++n) {
        ushort4 u;
        u.x = f2bf(fmaxf(acc[n][0], 0.f));
        u.y = f2bf(fmaxf(acc[n][1], 0.f));
        u.z = f2bf(fmaxf(acc[n][2], 0.f));
        u.w = f2bf(fmaxf(acc[n][3], 0.f));
        *(ushort4*)(&t_lds[(w * 16 + c) * T_STRIDE + n * 16 + g * 4]) = u;
    }
    __syncthreads();

    // ---- GEMM2: h^T = W2^T @ t^T ----
    short8 bf2[4];
#pragma unroll
    for (int kk = 0; kk < 4; ++kk)
        bf2[kk] = *(const short8*)(&t_lds[(w * 16 + c) * T_STRIDE + kk * 32 + g * 8]);

    f32x4 acc2[8];
#pragma unroll
    for (int n = 0; n < 8; ++n) {
        float4 bb = *(const float4*)(b2 + n * 16 + g * 4);
        acc2[n] = (f32x4){bb.x, bb.y, bb.z, bb.w};
    }
#pragma unroll
    for (int kk = 0; kk < 4; ++kk) {
#pragma unroll
        for (int n = 0; n < 8; ++n) {
            short8 af = *(const short8*)(Wb2t + (size_t)(n * 16 + c) * HDIM + kk * 32 + g * 8);
            acc2[n] = __builtin_amdgcn_mfma_f32_16x16x32_bf16(af, bf2[kk], acc2[n], 0, 0, 0);
        }
    }
    if (wrow0 + c < N) {
#pragma unroll
        for (int n = 0; n < 8; ++n) {
            ushort4 u;
            u.x = f2bf(fmaxf(acc2[n][0], 0.f));
            u.y = f2bf(fmaxf(acc2[n][1], 0.f));
            u.z = f2bf(fmaxf(acc2[n][2], 0.f));
            u.w = f2bf(fmaxf(acc2[n][3], 0.f));
            *(ushort4*)(h_out + (size_t)(wrow0 + c) * HDIM + n * 16 + g * 4) = u;
        }
    }
}

// ---------------- output projection (reads bf16 h) ----------------
__global__ void out_kernel(const uint32* __restrict__ hq, const float* __restrict__ Wout,
                           const float* __restrict__ bout, float* __restrict__ out, int N) {
    int idx = blockIdx.x * 256 + threadIdx.x;
    int n = idx >> 4, pe = idx & 15;
    if (n >= N) return;
    float acc = bout[pe];
#pragma unroll 8
    for (int k2 = 0; k2 < 64; ++k2) {
        uint32 g = hq[(size_t)n * 64 + k2];
        acc = fmaf(bflo(g), Wout[(2 * k2) * 16 + pe], acc);
        acc = fmaf(bfhi(g), Wout[(2 * k2 + 1) * 16 + pe], acc);
    }
    out[(size_t)n * 16 + pe] = acc;
}

extern "C" void kernel_launch(void* const* d_in, const int* in_sizes, int n_in,
                              void* d_out, int out_size, void* d_ws, size_t ws_size,
                              hipStream_t stream) {
    const int*   x_type     = (const int*)  d_in[0];
    const float* x_feat     = (const float*)d_in[1];
    const int*   edge_index = (const int*)  d_in[2];
    const float* edge_attr  = (const float*)d_in[3];
    const float* type_embed = (const float*)d_in[4];
    const float* featW      = (const float*)d_in[5];
    const float* featb      = (const float*)d_in[6];
    const float* edgeW      = (const float*)d_in[7];
    const float* edgeb      = (const float*)d_in[8];
    const float* W1         = (const float*)d_in[9];
    const float* b1         = (const float*)d_in[10];
    const float* W2         = (const float*)d_in[11];
    const float* b2         = (const float*)d_in[12];
    const float* eps        = (const float*)d_in[13];
    const float* Wout       = (const float*)d_in[14];
    const float* bout       = (const float*)d_in[15];

    const int N = in_sizes[0];
    const int E = in_sizes[2] / 2;
    const int L = in_sizes[13];
    const int N64 = (N + 63) & ~63;     // pad node buffers so MFMA tiles read in-bounds

    const int* srcIdx = edge_index;
    const int* dstIdx = edge_index + E;

    auto align256 = [](size_t x) { return (x + 255) & ~(size_t)255; };
    char* p = (char*)d_ws;
    ushort16* h_buf  = (ushort16*)p;           p += align256((size_t)N64 * HDIM * 2);
    ushort16* z_buf  = (ushort16*)p;           p += align256((size_t)N64 * HDIM * 2);
    int*   deg       = (int*)p;                p += align256((size_t)N * 4);
    int*   row_ptr   = (int*)p;                p += align256((size_t)(N + 1) * 4);
    int*   fill_ptr  = (int*)p;                p += align256((size_t)N * 4);
    int4*  adj       = (int4*)p;               p += align256((size_t)E * 16);
    int*   partials  = (int*)p;                p += align256(512 * 4);
    int*   offsets   = (int*)p;                p += align256(512 * 4);
    ushort16* Wb1t   = (ushort16*)p;           p += align256((size_t)L * HDIM * HDIM * 2);
    ushort16* Wb2t   = (ushort16*)p;           p += align256((size_t)L * HDIM * HDIM * 2);
    (void)ws_size;

    const int nb = (N + 255) / 256;   // 196 <= 256

    hipMemsetAsync(deg, 0, (size_t)N * 4, stream);
    count_kernel<<<(E + 255) / 256, 256, 0, stream>>>(dstIdx, deg, E);
    partial_kernel<<<nb, 256, 0, stream>>>(deg, partials, N);
    scan_partials_kernel<<<1, 256, 0, stream>>>(partials, offsets, nb, row_ptr, N, E);
    scatter_scan_kernel<<<nb, 256, 0, stream>>>(deg, offsets, row_ptr, fill_ptr, N);
    fill_kernel<<<(E + 255) / 256, 256, 0, stream>>>(srcIdx, dstIdx, edge_attr,
                                                     fill_ptr, adj, E);

    const int wtotal = L * HDIM * HDIM;
    prep_weights<<<(wtotal + 255) / 256, 256, 0, stream>>>(W1, W2, Wb1t, Wb2t, wtotal);

    embed_kernel<<<((size_t)N * HDIM + 255) / 256, 256, 0, stream>>>(
        x_type, x_feat, type_embed, featW, featb, h_buf, N);

    for (int l = 0; l < L; ++l) {
        agg_kernel<<<(N + 1) / 2, 128, 0, stream>>>(
            (const uint32*)h_buf, row_ptr, adj, edgeW, edgeb, eps, l,
            (uint32*)z_buf, N);
        mlp_mfma<<<N64 / 64, 256, 0, stream>>>(
            z_buf, Wb1t + (size_t)l * HDIM * HDIM, b1 + (size_t)l * HDIM,
            Wb2t + (size_t)l * HDIM * HDIM, b2 + (size_t)l * HDIM, h_buf, N);
    }

    out_kernel<<<((size_t)N * 16 + 255) / 256, 256, 0, stream>>>(
        (const uint32*)h_buf, Wout, bout, (float*)d_out, N);
}